// Round 17
// baseline (478.918 us; speedup 1.0000x reference)
//
#include <hip/hip_runtime.h>
#include <hip/hip_bf16.h>

// MAMBA_BayesMAGAC: B=32, L=512, D=128, E=64, HS=64, DTR=4, U=32, R=3, K=3, DE=10, NH=4
// Round 17: in-proj moved into prep5 (halo-recompute, xz never materialized; only
// compact res[row][64] written). opfn3 loses its in-proj tail (phases halved).
// gemm_in2 deleted. 12 dispatches. Co-schedule/tails as round 16.

#define B_ 32
#define L_ 512
#define D_ 128
#define E_ 64
#define HS_ 64

// ---- workspace offsets (floats) ----
#define OFF_X     0u          // 2,097,152  x [b][l][128]
#define OFF_RESF  2097152u    // 1,048,576  res (gate z) [b][l][64]
#define OFF_RESB  3145728u    //            (old XZ slot; XZB half now free)
#define OFF_XPF   6291456u    // 1,048,576  xp [b][l][64]
#define OFF_XPB   7340032u
#define OFF_PKF   8388608u    // 2,097,152  (dl,du) [b][l][64][2]
#define OFF_PKB   10485760u
#define OFF_XBCF  12582912u   // 1,048,576 u32 (ends 13,631,488)
#define OFF_WFT   13631488u   // 1,048,576  Wf [h][k][l][n]  (hole 1)
#define OFF_XBCB  14680064u   // 1,048,576 u32 (ends 15,728,640)
#define OFF_STT   15728640u   // 262,144    S^T (hole 2)
#define OFF_AEFF  15990784u   // 65,536     (ends 16,056,320 < YSF)
#define OFF_YSF   16777216u   // 1,048,576  scan y [b][e][l]
#define OFF_YSB   17825792u   // end 18,874,368 floats = 75.5 MB
// head: VB (bf16 V) over dead PK; PART over dead XBC/WfT/StT; RED1 over dead YSF.
#define OFF_VB    8388608u    // u32 x 4,194,304 (ends 12,582,912)
#define OFF_PART  12582912u   // 4,194,304 (ends 16,777,216)
#define OFF_RED1  16777216u   // 131,072

__device__ __forceinline__ float sigf(float x) { return 1.f / (1.f + __expf(-x)); }
__device__ __forceinline__ unsigned int bf16r(float x) {
    unsigned int u = __float_as_uint(x);
    return (u + 0x7fffu + ((u >> 16) & 1u)) >> 16;   // RNE to bf16, return low 16
}

// ---- head-precompute role bodies (device) ----
__device__ void role_wf(int bx0, int tid, const float* __restrict__ psi,
                        const float* __restrict__ F_w, float* __restrict__ WfT)
{
    const int idx = bx0 * 256 + tid;  // 2^20
    const int n = idx & 127, l = (idx >> 7) & 511, k = (idx >> 16) & 3, h = idx >> 18;
    float acc = 0.f;
#pragma unroll
    for (int d = 0; d < 10; ++d)
        acc = fmaf(psi[n * 10 + d], F_w[((h * 10 + d) * 4 + k) * 512 + l], acc);
    WfT[idx] = acc;
}

__device__ void role_qkaeff(int bx0, int tid, const float* __restrict__ psi,
                            const float* __restrict__ psis, const float* __restrict__ W_q,
                            const float* __restrict__ W_k, const float* __restrict__ attn_a,
                            float* __restrict__ Aeff, float* __restrict__ StT,
                            float* sQ2 /*>=32 fl*/, float* red2 /*>=256 fl*/)
{
    const int half = tid >> 7, mcol = tid & 127;
    const int unit = bx0 * 2 + half;                 // 0..511
    const int h = unit >> 7, n = unit & 127;
    float Kreg[10];
#pragma unroll
    for (int d = 0; d < 10; ++d) Kreg[d] = 0.f;
#pragma unroll
    for (int d0 = 0; d0 < 10; ++d0) {
        const float pv = psi[mcol * 10 + d0];
#pragma unroll
        for (int d = 0; d < 10; ++d) Kreg[d] = fmaf(pv, W_k[(d0 * 4 + h) * 10 + d], Kreg[d]);
    }
    if (mcol < 10) {
        float qd = 0.f;
        for (int d0 = 0; d0 < 10; ++d0)
            qd = fmaf(psi[n * 10 + d0], W_q[(d0 * 4 + h) * 10 + mcol], qd);
        sQ2[half * 16 + mcol] = qd;
    }
    __syncthreads();
    float d2 = 0.f;
#pragma unroll
    for (int d = 0; d < 10; ++d) { const float df = psi[n * 10 + d] - psi[mcol * 10 + d]; d2 = fmaf(df, df, d2); }
    const float gv = __expf(-psis[0] * d2);
    float qv = 0.f;
#pragma unroll
    for (int d = 0; d < 10; ++d) qv = fmaf(sQ2[half * 16 + d], Kreg[d], qv);
    qv *= 0.3162277660168379332f;  // 1/sqrt(10)
    float* rd = red2 + half * 128;
    float r;
    rd[mcol] = gv; __syncthreads();
    for (int s = 64; s >= 1; s >>= 1) { if (mcol < s) rd[mcol] = fmaxf(rd[mcol], rd[mcol + s]); __syncthreads(); }
    r = rd[0]; __syncthreads();
    const float eg = __expf(gv - r);
    rd[mcol] = eg; __syncthreads();
    for (int s = 64; s >= 1; s >>= 1) { if (mcol < s) rd[mcol] += rd[mcol + s]; __syncthreads(); }
    const float gsum = rd[0]; __syncthreads();
    rd[mcol] = qv; __syncthreads();
    for (int s = 64; s >= 1; s >>= 1) { if (mcol < s) rd[mcol] = fmaxf(rd[mcol], rd[mcol + s]); __syncthreads(); }
    r = rd[0]; __syncthreads();
    const float eq = __expf(qv - r);
    rd[mcol] = eq; __syncthreads();
    for (int s = 64; s >= 1; s >>= 1) { if (mcol < s) rd[mcol] += rd[mcol + s]; __syncthreads(); }
    const float qsum = rd[0];
    const float al = sigf(attn_a[0]);
    const float aeff = al * (eg / gsum) + (1.f - al) * (eq / qsum);
    Aeff[h * 16384 + n * 128 + mcol] = aeff;
    StT[((h * 4 + 1) * 128 + mcol) * 128 + n] = aeff;
    StT[((h * 4 + 0) * 128 + mcol) * 128 + n] = (mcol == n) ? 1.f : 0.f;
}

__device__ void role_cheb(int bx0, int tid, const float* __restrict__ Aeff,
                          float* __restrict__ StT, int kk)
{
    const int h = bx0 >> 6;
    const int m0 = ((bx0 & 63) << 1) + (tid >> 7);
    const int n = tid & 127;
    const float* Ar = Aeff + h * 16384 + n * 128;
    const float* Sp = StT + ((h * 4 + kk - 1) * 128 + m0) * 128;
    float acc = 0.f;
#pragma unroll 8
    for (int p = 0; p < 128; ++p) acc = fmaf(Ar[p], Sp[p], acc);
    const float s2 = StT[((h * 4 + kk - 2) * 128 + m0) * 128 + n];
    StT[((h * 4 + kk) * 128 + m0) * 128 + n] = 2.f * acc - s2;
}

// V precompute (bf16 out): bx0 in [0,1024)
__device__ void role_v4(int bx0, int tid, const float* __restrict__ StT,
                        const float* __restrict__ WfT, const float* __restrict__ hmix,
                        unsigned int* __restrict__ Vb)
{
    const float m0 = hmix[0], m1 = hmix[1], m2 = hmix[2], m3 = hmix[3];
    const float mxx = fmaxf(fmaxf(m0, m1), fmaxf(m2, m3));
    const float e0 = __expf(m0 - mxx), e1 = __expf(m1 - mxx), e2 = __expf(m2 - mxx), e3 = __expf(m3 - mxx);
    const float inv = 1.f / (e0 + e1 + e2 + e3);
    const float mixv[4] = {e0 * inv, e1 * inv, e2 * inv, e3 * inv};
    const int lt = bx0 & 63, mm = bx0 >> 6;
    const int n4 = tid & 31, mh = tid >> 5;
    const int m = mm * 8 + mh;
    const int l0 = lt * 8, n0 = n4 * 4;
    float4 sv[16];
#pragma unroll
    for (int h = 0; h < 4; ++h) {
        const float mx = mixv[h];
#pragma unroll
        for (int k = 0; k < 4; ++k) {
            const float4 v = *(const float4*)&StT[(size_t)((h * 4 + k) * 128 + m) * 128 + n0];
            sv[h * 4 + k] = float4{v.x * mx, v.y * mx, v.z * mx, v.w * mx};
        }
    }
#pragma unroll
    for (int j = 0; j < 8; ++j) {
        const int l = l0 + j;
        float4 acc = {0.f, 0.f, 0.f, 0.f};
#pragma unroll
        for (int hk = 0; hk < 16; ++hk) {
            const float4 w = *(const float4*)&WfT[(size_t)(hk * 512 + l) * 128 + n0];
            acc.x = fmaf(sv[hk].x, w.x, acc.x);
            acc.y = fmaf(sv[hk].y, w.y, acc.y);
            acc.z = fmaf(sv[hk].z, w.z, acc.z);
            acc.w = fmaf(sv[hk].w, w.w, acc.w);
        }
        const uint2 p = uint2{(bf16r(acc.y) << 16) | bf16r(acc.x),
                              (bf16r(acc.w) << 16) | bf16r(acc.z)};
        *(uint2*)&Vb[(size_t)(l * 128 + m) * 64 + (n0 >> 1)] = p;
    }
}

// ------------- prep5: in-proj (halo) + conv + silu + xproj + delta + res-write -------------
// grid 2048 (+tails). Block = (dir, 16 rows of batch b). Computes xz locally (cols 0:64
// for conv; cols 64:128 = res written compact). No global xz.
__global__ __launch_bounds__(256) void prep5_kernel(
    const float* __restrict__ Xc, const float* __restrict__ in_w,
    const float* __restrict__ conv_w, const float* __restrict__ conv_b,
    const float* __restrict__ xproj_w, const float* __restrict__ dt_w,
    const float* __restrict__ dt_b, int layer,
    float* __restrict__ xpF_, float* __restrict__ xpB_,
    unsigned int* __restrict__ xbcF_, unsigned int* __restrict__ xbcB_,
    float* __restrict__ pkF_, float* __restrict__ pkB_,
    float* __restrict__ resF_, float* __restrict__ resB_,
    const float* __restrict__ psi, const float* __restrict__ F_w, float* __restrict__ WfT,
    const float* __restrict__ Aeff, float* __restrict__ StT)
{
    __shared__ float smem[9536];
    // phase A: sx [0,2560), sWin [2560,6656), sxz [6656,7936)
    // phase B: sWx [0,8448), sxp4 [8448,9472), sdl4 [9472,9536)
    float* sx   = smem;
    float* sWin = smem + 2560;
    float* sxz  = smem + 6656;
    float* sWx  = smem;
    float* sxp4 = smem + 8448;
    float* sdl4 = smem + 9472;
    const int tid = threadIdx.x, wv = tid >> 6, lane = tid & 63;
    if (blockIdx.x >= 2048) {
        const int bx0 = blockIdx.x - 2048;
        if (layer == 0) role_wf(bx0, tid, psi, F_w, WfT);
        else            role_cheb(bx0, tid, Aeff, StT, 3);
        return;
    }
    const int dir = (int)(blockIdx.x >= 1024);        // block-uniform
    const int r0 = (blockIdx.x & 1023) * 16;          // 16 rows, same b
    const int b = r0 >> 9;
    const int l0 = r0 & 511;
    const int m = layer * 2 + dir;
    float* xp  = dir ? xpB_  : xpF_;
    unsigned int* xbc = dir ? xbcB_ : xbcF_;
    float* pkx = dir ? pkB_  : pkF_;
    float* res = dir ? resB_ : resF_;
    // hoisted per-lane consts
    const float* cw = conv_w + m * 192 + lane * 3;
    const float cw0 = cw[0], cw1 = cw[1], cw2 = cw[2];
    const float cb  = conv_b[m * 64 + lane];
    const float dtb = dt_b[m * 64 + lane];
    const float* dwp = dt_w + m * 256;
    const float dw0 = dwp[lane], dw1 = dwp[64 + lane], dw2 = dwp[128 + lane], dw3 = dwp[192 + lane];

    // stage x rows local 0..19 (l = l0-2+lr), zero outside batch
    for (int q = tid; q < 640; q += 256) {
        const int lr = q >> 5, c4 = q & 31;
        const int l = l0 - 2 + lr;
        float4 v = float4{0.f, 0.f, 0.f, 0.f};
        if (l >= 0 && l < 512) v = *(const float4*)&Xc[(size_t)(b * 512 + l) * 128 + c4 * 4];
        *(float4*)&sx[lr * 128 + c4 * 4] = v;
    }
    // in-proj GEMM (4 k-chunks of 32). Wave wv: xp rows local 5wv..5wv+4 (20 total);
    // res rows = own rows local 2+4wv..2+4wv+3.
    float accx[5] = {0.f, 0.f, 0.f, 0.f, 0.f};
    float accr[4] = {0.f, 0.f, 0.f, 0.f};
    const float* Wg2 = in_w + m * 16384;
    for (int kc = 0; kc < 4; ++kc) {
        __syncthreads();   // kc=0: sx staged; else: sWin readers done
        for (int q = tid; q < 1024; q += 256) {
            const int kk = q >> 5, c4 = q & 31;
            *(float4*)&sWin[kk * 128 + c4 * 4] = *(const float4*)&Wg2[(kc * 32 + kk) * 128 + c4 * 4];
        }
        __syncthreads();
#pragma unroll 8
        for (int kk = 0; kk < 32; ++kk) {
            const float wx = sWin[kk * 128 + lane];
            const float wr = sWin[kk * 128 + 64 + lane];
            const int kg = kc * 32 + kk;
            accx[0] = fmaf(sx[(5 * wv + 0) * 128 + kg], wx, accx[0]);
            accx[1] = fmaf(sx[(5 * wv + 1) * 128 + kg], wx, accx[1]);
            accx[2] = fmaf(sx[(5 * wv + 2) * 128 + kg], wx, accx[2]);
            accx[3] = fmaf(sx[(5 * wv + 3) * 128 + kg], wx, accx[3]);
            accx[4] = fmaf(sx[(5 * wv + 4) * 128 + kg], wx, accx[4]);
            accr[0] = fmaf(sx[(2 + 4 * wv + 0) * 128 + kg], wr, accr[0]);
            accr[1] = fmaf(sx[(2 + 4 * wv + 1) * 128 + kg], wr, accr[1]);
            accr[2] = fmaf(sx[(2 + 4 * wv + 2) * 128 + kg], wr, accr[2]);
            accr[3] = fmaf(sx[(2 + 4 * wv + 3) * 128 + kg], wr, accr[3]);
        }
    }
    // write xz-local (cols 0:64) + res (global, own rows)
#pragma unroll
    for (int j = 0; j < 5; ++j) sxz[(5 * wv + j) * 64 + lane] = accx[j];
#pragma unroll
    for (int j = 0; j < 4; ++j) res[(size_t)(r0 + 4 * wv + j) * 64 + lane] = accr[j];
    __syncthreads();   // sxz visible to all waves
    // conv + silu (cross-wave sxz rows; halo rows are exact zeros where l OOB)
    float uu[4];
#pragma unroll
    for (int it = 0; it < 4; ++it) {
        const int lloc = 2 + wv * 4 + it;
        const int o1 = dir ? 1 : -1;
        const float x0 = sxz[lloc * 64 + lane];
        const float x1 = sxz[(lloc + o1) * 64 + lane];
        const float x2 = sxz[(lloc + 2 * o1) * 64 + lane];
        float acc = cb + cw0 * x2 + cw1 * x1 + cw2 * x0;
        const float u = acc * sigf(acc);
        xp[(size_t)(r0 + wv * 4 + it) * 64 + lane] = u;
        uu[it] = u;
    }
    __syncthreads();   // all conv reads of sxz done; smem reusable
    // phase B: stage xproj W + u broadcast
    const float* Wg = xproj_w + m * 8448;
    for (int q = tid; q < 2112; q += 256) ((float4*)sWx)[q] = ((const float4*)Wg)[q];
    *(float4*)&sxp4[(wv * 64 + lane) * 4] = float4{uu[0], uu[1], uu[2], uu[3]};
    __syncthreads();
    const int jdt = lane & 3;
    float aB[4] = {0.f, 0.f, 0.f, 0.f};
    float aC[4] = {0.f, 0.f, 0.f, 0.f};
    float adt[4] = {0.f, 0.f, 0.f, 0.f};
#pragma unroll 4
    for (int k = 0; k < 64; ++k) {
        const float wB = sWx[k * 132 + 4 + lane];
        const float wC = sWx[k * 132 + 68 + lane];
        const float wd = sWx[k * 132 + jdt];
        const float4 xv = *(const float4*)&sxp4[(wv * 64 + k) * 4];
        aB[0] = fmaf(xv.x, wB, aB[0]); aC[0] = fmaf(xv.x, wC, aC[0]); adt[0] = fmaf(xv.x, wd, adt[0]);
        aB[1] = fmaf(xv.y, wB, aB[1]); aC[1] = fmaf(xv.y, wC, aC[1]); adt[1] = fmaf(xv.y, wd, adt[1]);
        aB[2] = fmaf(xv.z, wB, aB[2]); aC[2] = fmaf(xv.z, wC, aC[2]); adt[2] = fmaf(xv.z, wd, adt[2]);
        aB[3] = fmaf(xv.w, wB, aB[3]); aC[3] = fmaf(xv.w, wC, aC[3]); adt[3] = fmaf(xv.w, wd, adt[3]);
    }
#pragma unroll
    for (int it = 0; it < 4; ++it) {
        const int row = r0 + wv * 4 + it;
        xbc[row * 64 + lane] = (bf16r(aC[it]) << 16) | bf16r(aB[it]);
        if (lane < 4) sdl4[(wv * 4 + it) * 4 + lane] = adt[it];
    }
#pragma unroll
    for (int it = 0; it < 4; ++it) {
        const int row = r0 + wv * 4 + it;
        float dpre = fmaf(sdl4[(wv * 4 + it) * 4 + 0], dw0, dtb);
        dpre = fmaf(sdl4[(wv * 4 + it) * 4 + 1], dw1, dpre);
        dpre = fmaf(sdl4[(wv * 4 + it) * 4 + 2], dw2, dpre);
        dpre = fmaf(sdl4[(wv * 4 + it) * 4 + 3], dw3, dpre);
        const float dlt = (dpre > 20.f) ? dpre : log1pf(__expf(dpre));
        ((float2*)pkx)[row * 64 + lane] = float2{dlt, dlt * uu[it]};
    }
}

// ------------- selective scan v8 + (tail: qkaeff). grid 1024(+256), block 256 -------------
__global__ __launch_bounds__(256, 4) void scan8_kernel(
    const unsigned int* __restrict__ xbcF, const unsigned int* __restrict__ xbcB,
    const float* __restrict__ pkF, const float* __restrict__ pkB,
    const float* __restrict__ AlogF, const float* __restrict__ AlogB,
    float* __restrict__ ysF, float* __restrict__ ysB,
    const float* __restrict__ psi, const float* __restrict__ psis,
    const float* __restrict__ W_q, const float* __restrict__ W_k,
    const float* __restrict__ attn_a, float* __restrict__ Aeff, float* __restrict__ StT)
{
    __shared__ unsigned int sbc[2][1024]; // 8 KB
    __shared__ float spk[2][4][16][2];    // 1 KB
    __shared__ float ytile[4][16][68];    // 17.4 KB
    const int tid = threadIdx.x, wv = tid >> 6, lane = tid & 63;
    const int bx = blockIdx.x;
    if (bx >= 1024) {
        role_qkaeff(bx - 1024, tid, psi, psis, W_q, W_k, attn_a, Aeff, StT,
                    (float*)&sbc[1][0], (float*)&sbc[0][0]);
        return;
    }
    const int db = bx & 63;               // (dir,b) in low bits -> same XCD for all e-quads
    const int dir = db >> 5;
    const int b   = db & 31;
    const int e0  = (bx >> 6) * 4;
    const int e   = e0 + wv;
    const unsigned int* xbc = dir ? xbcB : xbcF;
    const float* pk  = dir ? pkB  : pkF;
    const float* Aw  = dir ? AlogB : AlogF;
    float* ys = dir ? ysB : ysF;
    const float a2 = -__expf(Aw[e * 64 + lane]) * 1.4426950408889634f;  // prescaled log2e
    float s = 0.f;
    float* yrow = ys + (size_t)(b * 64 + e) * 512;

    const int psl = tid & 15, pw_ = tid >> 4;

#define STG_LOAD(RS)                                                              \
    {                                                                             \
        nb = *(const uint4*)(xbc + (size_t)(RS) * 64 + tid * 4);                  \
        if (tid < 64)                                                             \
            npp = *(const float2*)(pk + (size_t)((RS) + psl) * 128 + (e0 + pw_) * 2); \
    }
#define STG_WRITE(BUF)                                                            \
    {                                                                             \
        *(uint4*)(&sbc[BUF][tid * 4]) = nb;                                       \
        if (tid < 64) *(float2*)(&spk[BUF][pw_][psl][0]) = npp;                   \
    }

#define SCAN16(REV)                                                               \
    {                                                                             \
        const unsigned int* bc = &sbc[cur][0];                                    \
        const float* pq = &spk[cur][wv][0][0];                                    \
        _Pragma("unroll")                                                         \
        for (int j = 0; j < 8; ++j) {                                             \
            const int pj = (REV) ? 7 - j : j;                                     \
            const float4 pk4 = *(const float4*)(pq + pj * 4);                     \
            const int sA = (REV) ? 15 - 2 * j : 2 * j;                            \
            const int sB = (REV) ? 14 - 2 * j : 2 * j + 1;                        \
            const float dlA = (REV) ? pk4.z : pk4.x;                              \
            const float duA = (REV) ? pk4.w : pk4.y;                              \
            const float dlB = (REV) ? pk4.x : pk4.z;                              \
            const float duB = (REV) ? pk4.y : pk4.w;                              \
            const unsigned int bA = bc[sA * 64 + lane];                           \
            const float BnA = __uint_as_float(bA << 16);                          \
            const float CnA = __uint_as_float(bA & 0xffff0000u);                  \
            s = fmaf(__builtin_amdgcn_exp2f(dlA * a2), s, duA * BnA);             \
            ytile[wv][sA][lane] = s * CnA;                                        \
            const unsigned int bB = bc[sB * 64 + lane];                           \
            const float BnB = __uint_as_float(bB << 16);                          \
            const float CnB = __uint_as_float(bB & 0xffff0000u);                  \
            s = fmaf(__builtin_amdgcn_exp2f(dlB * a2), s, duB * BnB);             \
            ytile[wv][sB][lane] = s * CnB;                                        \
        }                                                                         \
    }

    // prologue: stage tile 0
    {
        uint4 nb; float2 npp;
        const int rs0 = b * 512 + (dir ? 496 : 0);
        STG_LOAD(rs0);
        STG_WRITE(0);
    }
    __syncthreads();

    int cur = 0;
    const int rr = lane & 15, sg = lane >> 4;
    for (int t = 0; t < 32; ++t) {
        uint4 nb; float2 npp;
        const bool more = (t + 1) < 32;
        if (more) {
            const int rs = b * 512 + (dir ? (496 - (t + 1) * 16) : ((t + 1) * 16));
            STG_LOAD(rs);
        }
        if (dir == 0) { SCAN16(0) } else { SCAN16(1) }
        {
            const float* yt = &ytile[wv][rr][sg * 16];
            const float4 A0 = *(const float4*)yt;
            const float4 A1 = *(const float4*)(yt + 4);
            const float4 A2 = *(const float4*)(yt + 8);
            const float4 A3 = *(const float4*)(yt + 12);
            float p = ((A0.x + A0.y) + (A0.z + A0.w)) + ((A1.x + A1.y) + (A1.z + A1.w))
                    + ((A2.x + A2.y) + (A2.z + A2.w)) + ((A3.x + A3.y) + (A3.z + A3.w));
            p += __shfl_xor(p, 16);
            p += __shfl_xor(p, 32);
            if (lane < 16) {
                // slot rr: dir=0 -> l = t*16+rr ; dir=1 -> l = 496 + rr - t*16
                const int lg = dir ? (496 + rr - t * 16) : (t * 16 + rr);
                yrow[lg] = p;
            }
        }
        if (more) STG_WRITE(cur ^ 1);
        __syncthreads();
        cur ^= 1;
    }
#undef STG_LOAD
#undef STG_WRITE
#undef SCAN16
}

// ------------- opfn4: gate + out-proj + LN1 + FFN + LN2 (no in-proj tail) ------------------
// grid 512 (+tails: layer0 -> cheb2, layer2 -> v4). block 256.
__global__ __launch_bounds__(256, 4) void opfn4_kernel(
    const float* __restrict__ ysF, const float* __restrict__ ysB,
    const float* __restrict__ xpF, const float* __restrict__ xpB,
    const float* __restrict__ resF, const float* __restrict__ resB,
    const float* __restrict__ Dp, int layer,
    const float* __restrict__ Xc, const float* __restrict__ out_w,
    const float* __restrict__ W1, const float* __restrict__ b1,
    const float* __restrict__ W2, const float* __restrict__ b2,
    const float* __restrict__ g1, const float* __restrict__ bb1,
    const float* __restrict__ g2, const float* __restrict__ bb2,
    float* __restrict__ xout,
    const float* __restrict__ Aeff, float* __restrict__ StT,
    const float* __restrict__ WfT, const float* __restrict__ hmix,
    unsigned int* __restrict__ Vb)
{
    __shared__ float smem[9216];
    float* syy = smem;            // [32][128]: sy (gated), then y3 (time-shared)
    float* sw  = smem + 4096;     // [32][128] weight chunk / W1 / W2
    float* sh  = smem + 8192;     // [32][32]
    const int tid = threadIdx.x;
    if (blockIdx.x >= 512) {
        const int bx0 = blockIdx.x - 512;
        if (layer == 0) role_cheb(bx0, tid, Aeff, StT, 2);
        else            role_v4(bx0, tid, StT, WfT, hmix, Vb);   // layer 2 only
        return;
    }
    const int r0 = blockIdx.x * 32;
    const int b = r0 >> 9, l0 = r0 & 511;
    const int wv = tid >> 6, lane = tid & 63;
    const float* WFp = out_w + (layer * 2) * 8192;
    const float* WBp = out_w + (layer * 2 + 1) * 8192;

    // phase 0: gated transpose: sy[r][d*64+e] = (ys + xp*D) * sigmoid(res)
    for (int q = tid; q < 1024; q += 256) {
        const int d = q >> 9, ee = (q >> 3) & 63, rq = q & 7;
        const float* ysp = d ? ysB : ysF;
        const float4 v = *(const float4*)&ysp[(size_t)(b * 64 + ee) * 512 + l0 + rq * 4];
        const float dv = Dp[(layer * 2 + d) * 64 + ee];
        const float* xpp = d ? xpB : xpF;
        const float* rsp = d ? resB : resF;
        const float vv[4] = {v.x, v.y, v.z, v.w};
#pragma unroll
        for (int j = 0; j < 4; ++j) {
            const int r = rq * 4 + j;
            const int row = r0 + r;
            const float u   = xpp[(size_t)row * 64 + ee];
            const float rsv = rsp[(size_t)row * 64 + ee];
            syy[r * 128 + d * 64 + ee] = (vv[j] + u * dv) * sigf(rsv);
        }
    }
    __syncthreads();

    // phase 2: out-proj GEMM (4 chunks of 32 k-rows) + residual + LN1 -> y3 (in syy)
    float acc[8][2];
#pragma unroll
    for (int r = 0; r < 8; ++r) { acc[r][0] = 0.f; acc[r][1] = 0.f; }
#define OPSTEP8(COMP, J)                                                          \
        {                                                                         \
            const float w0 = sw[(kk + (J)) * 128 + lane];                         \
            const float w1 = sw[(kk + (J)) * 128 + lane + 64];                    \
            acc[0][0] = fmaf(y40.COMP, w0, acc[0][0]); acc[0][1] = fmaf(y40.COMP, w1, acc[0][1]); \
            acc[1][0] = fmaf(y41.COMP, w0, acc[1][0]); acc[1][1] = fmaf(y41.COMP, w1, acc[1][1]); \
            acc[2][0] = fmaf(y42.COMP, w0, acc[2][0]); acc[2][1] = fmaf(y42.COMP, w1, acc[2][1]); \
            acc[3][0] = fmaf(y43.COMP, w0, acc[3][0]); acc[3][1] = fmaf(y43.COMP, w1, acc[3][1]); \
            acc[4][0] = fmaf(y44.COMP, w0, acc[4][0]); acc[4][1] = fmaf(y44.COMP, w1, acc[4][1]); \
            acc[5][0] = fmaf(y45.COMP, w0, acc[5][0]); acc[5][1] = fmaf(y45.COMP, w1, acc[5][1]); \
            acc[6][0] = fmaf(y46.COMP, w0, acc[6][0]); acc[6][1] = fmaf(y46.COMP, w1, acc[6][1]); \
            acc[7][0] = fmaf(y47.COMP, w0, acc[7][0]); acc[7][1] = fmaf(y47.COMP, w1, acc[7][1]); \
        }
#define GEMM_CHUNK8(SRC, KO)                                                      \
    _Pragma("unroll")                                                             \
    for (int kk = 0; kk < 32; kk += 4) {                                          \
        const float4 y40 = *(const float4*)&(SRC)[(wv * 8 + 0) * 128 + (KO) + kk];\
        const float4 y41 = *(const float4*)&(SRC)[(wv * 8 + 1) * 128 + (KO) + kk];\
        const float4 y42 = *(const float4*)&(SRC)[(wv * 8 + 2) * 128 + (KO) + kk];\
        const float4 y43 = *(const float4*)&(SRC)[(wv * 8 + 3) * 128 + (KO) + kk];\
        const float4 y44 = *(const float4*)&(SRC)[(wv * 8 + 4) * 128 + (KO) + kk];\
        const float4 y45 = *(const float4*)&(SRC)[(wv * 8 + 5) * 128 + (KO) + kk];\
        const float4 y46 = *(const float4*)&(SRC)[(wv * 8 + 6) * 128 + (KO) + kk];\
        const float4 y47 = *(const float4*)&(SRC)[(wv * 8 + 7) * 128 + (KO) + kk];\
        OPSTEP8(x, 0) OPSTEP8(y, 1) OPSTEP8(z, 2) OPSTEP8(w, 3)                  \
    }
    for (int koi = 0; koi < 4; ++koi) {
        if (koi) __syncthreads();        // readers of sw done
        for (int q = tid; q < 1024; q += 256) {
            const int kk = q >> 5, c4 = q & 31;
            const int kg = koi * 32 + kk;
            *(float4*)&sw[kk * 128 + c4 * 4] = (kg < 64)
                ? *(const float4*)&WFp[kg * 128 + c4 * 4]
                : *(const float4*)&WBp[(kg - 64) * 128 + c4 * 4];
        }
        __syncthreads();
        GEMM_CHUNK8(syy, koi * 32);
    }
    __syncthreads();       // all sy + sw reads done
    // stage W1 (sw free) + LN1 -> y3 (syy free)
    for (int q = tid; q < 1024; q += 256) ((float4*)sw)[q] = ((const float4*)W1)[q];
#pragma unroll
    for (int r = 0; r < 8; ++r) {
        const int rl = wv * 8 + r;
        const int row = r0 + rl;
        float v0 = acc[r][0] + Xc[(size_t)row * 128 + lane];
        float v1 = acc[r][1] + Xc[(size_t)row * 128 + lane + 64];
        float sum = v0 + v1, sq = v0 * v0 + v1 * v1;
#pragma unroll
        for (int o = 32; o >= 1; o >>= 1) { sum += __shfl_xor(sum, o); sq += __shfl_xor(sq, o); }
        const float mean = sum * (1.f / 128.f);
        const float var = sq * (1.f / 128.f) - mean * mean;
        const float rs = rsqrtf(var + 1e-5f);
        syy[rl * 128 + lane]      = (v0 - mean) * rs * g1[lane] + bb1[lane];
        syy[rl * 128 + lane + 64] = (v1 - mean) * rs * g1[lane + 64] + bb1[lane + 64];
    }
    __syncthreads();
    // phase 3: hid = relu(y3 @ W1 + b1) -> sh  (thread: row=tid>>3, 4 u's)
    {
        const int r = tid >> 3, ug = (tid & 7) * 4;
        float h0 = b1[ug], h1 = b1[ug + 1], h2 = b1[ug + 2], h3 = b1[ug + 3];
#pragma unroll 8
        for (int k = 0; k < 128; ++k) {
            const float xv = syy[r * 128 + k];
            h0 = fmaf(xv, sw[k * 32 + ug], h0);
            h1 = fmaf(xv, sw[k * 32 + ug + 1], h1);
            h2 = fmaf(xv, sw[k * 32 + ug + 2], h2);
            h3 = fmaf(xv, sw[k * 32 + ug + 3], h3);
        }
        sh[r * 32 + ug]     = fmaxf(h0, 0.f);
        sh[r * 32 + ug + 1] = fmaxf(h1, 0.f);
        sh[r * 32 + ug + 2] = fmaxf(h2, 0.f);
        sh[r * 32 + ug + 3] = fmaxf(h3, 0.f);
    }
    __syncthreads();
    // stage W2 (sw free after phase 3)
    for (int q = tid; q < 1024; q += 256) ((float4*)sw)[q] = ((const float4*)W2)[q];
    __syncthreads();
    // phase 4: FFN2 + residual(y3) + LN2 -> xout
#pragma unroll
    for (int r = 0; r < 8; ++r) {
        const int rl = wv * 8 + r;
        float a0 = b2[lane], a1 = b2[lane + 64];
#pragma unroll 8
        for (int k = 0; k < 32; ++k) {
            const float hv = sh[rl * 32 + k];
            a0 = fmaf(hv, sw[k * 128 + lane], a0);
            a1 = fmaf(hv, sw[k * 128 + lane + 64], a1);
        }
        const float v0 = a0 + syy[rl * 128 + lane];
        const float v1 = a1 + syy[rl * 128 + lane + 64];
        float sum = v0 + v1, sq = v0 * v0 + v1 * v1;
#pragma unroll
        for (int o = 32; o >= 1; o >>= 1) { sum += __shfl_xor(sum, o); sq += __shfl_xor(sq, o); }
        const float mean = sum * (1.f / 128.f);
        const float var = sq * (1.f / 128.f) - mean * mean;
        const float rs = rsqrtf(var + 1e-5f);
        const int row = r0 + rl;
        xout[(size_t)row * 128 + lane]      = (v0 - mean) * rs * g2[lane] + bb2[lane];
        xout[(size_t)row * 128 + lane + 64] = (v1 - mean) * rs * g2[lane + 64] + bb2[lane + 64];
    }
}

// ================= head (post-layer) =================
__global__ __launch_bounds__(256) void head_ctr_kernel(
    const float* __restrict__ Xf, const unsigned int* __restrict__ Vb,
    float* __restrict__ partial)
{
    __shared__ float sx[32][128];
    const int l = blockIdx.x, tid = threadIdx.x;
    const int n = tid & 127, mh = tid >> 7;
    for (int q = tid; q < 1024; q += 256) {
        const int b = q >> 5, m4 = q & 31;
        *(float4*)&sx[b][m4 * 4] = *(const float4*)&Xf[(size_t)(b * 512 + l) * 128 + m4 * 4];
    }
    __syncthreads();
    float acc[32];
#pragma unroll
    for (int b = 0; b < 32; ++b) acc[b] = 0.f;
    const unsigned int* vp = Vb + (size_t)(l * 128 + mh * 64) * 64 + (n >> 1);
    const bool hi = (n & 1);
    for (int mm = 0; mm < 64; ++mm) {
        const unsigned int u = vp[(size_t)mm * 64];
        const float v = __uint_as_float(hi ? (u & 0xffff0000u) : (u << 16));
        const int m = mh * 64 + mm;
#pragma unroll
        for (int b = 0; b < 32; ++b) acc[b] = fmaf(sx[b][m], v, acc[b]);
    }
#pragma unroll
    for (int b = 0; b < 32; ++b)
        partial[(size_t)((l * 2 + mh) * 32 + b) * 128 + n] = acc[b];
}

__global__ __launch_bounds__(128) void head_red_kernel(
    const float* __restrict__ partial, float* __restrict__ red1)
{
    const int b = blockIdx.x >> 5, cs = blockIdx.x & 31, n = threadIdx.x;
    const float* p = partial + ((size_t)(cs * 32) * 32 + b) * 128 + n;
    float s = 0.f;
#pragma unroll 8
    for (int c = 0; c < 32; ++c) s += p[(size_t)c * 4096];
    red1[(b * 32 + cs) * 128 + n] = s;
}

__global__ __launch_bounds__(128) void head_out_kernel(
    const float* __restrict__ red1, const float* __restrict__ psi,
    const float* __restrict__ f_b, const float* __restrict__ hmix,
    const float* __restrict__ head_w, const float* __restrict__ head_b, float* __restrict__ out)
{
    __shared__ float red[128];
    const int b = blockIdx.x, n = threadIdx.x;
    const float m0 = hmix[0], m1 = hmix[1], m2 = hmix[2], m3 = hmix[3];
    const float mxx = fmaxf(fmaxf(m0, m1), fmaxf(m2, m3));
    const float e0 = __expf(m0 - mxx), e1 = __expf(m1 - mxx), e2 = __expf(m2 - mxx), e3 = __expf(m3 - mxx);
    const float inv = 1.f / (e0 + e1 + e2 + e3);
    const float mixv[4] = {e0 * inv, e1 * inv, e2 * inv, e3 * inv};
    float s = 0.f;
#pragma unroll
    for (int h = 0; h < 4; ++h) {
        float t = 0.f;
#pragma unroll
        for (int d = 0; d < 10; ++d) t = fmaf(psi[n * 10 + d], f_b[h * 10 + d], t);
        s = fmaf(mixv[h], t, s);
    }
#pragma unroll 8
    for (int cs = 0; cs < 32; ++cs) s += red1[(b * 32 + cs) * 128 + n];
    red[n] = s * head_w[n];
    __syncthreads();
    for (int st = 64; st >= 1; st >>= 1) { if (n < st) red[n] += red[n + st]; __syncthreads(); }
    if (n == 0) out[b] = red[0] + head_b[0];
    out[32 + b * 128 + n] = 0.f;   // log_var = zeros
}

extern "C" void kernel_launch(void* const* d_in, const int* in_sizes, int n_in,
                              void* d_out, int out_size, void* d_ws, size_t ws_size,
                              hipStream_t stream) {
    const float* x_in    = (const float*)d_in[0];
    const float* in_w    = (const float*)d_in[1];
    const float* conv_w  = (const float*)d_in[2];
    const float* conv_b  = (const float*)d_in[3];
    const float* xproj_w = (const float*)d_in[4];
    const float* dt_w    = (const float*)d_in[5];
    const float* dt_b    = (const float*)d_in[6];
    const float* Alog    = (const float*)d_in[7];
    const float* Dp      = (const float*)d_in[8];
    const float* out_w   = (const float*)d_in[9];
    const float* ln1_g   = (const float*)d_in[10];
    const float* ln1_b   = (const float*)d_in[11];
    const float* ln2_g   = (const float*)d_in[12];
    const float* ln2_b   = (const float*)d_in[13];
    const float* ffn_w1  = (const float*)d_in[14];
    const float* ffn_b1  = (const float*)d_in[15];
    const float* ffn_w2  = (const float*)d_in[16];
    const float* ffn_b2  = (const float*)d_in[17];
    const float* psi_emb = (const float*)d_in[18];
    const float* psi_s   = (const float*)d_in[19];
    const float* W_q     = (const float*)d_in[20];
    const float* W_k     = (const float*)d_in[21];
    const float* attn_a  = (const float*)d_in[22];
    const float* F_w     = (const float*)d_in[23];
    const float* f_b     = (const float*)d_in[24];
    const float* hmix    = (const float*)d_in[25];
    const float* head_w  = (const float*)d_in[26];
    const float* head_b  = (const float*)d_in[27];
    float* ws = (float*)d_ws;
    float* outp = (float*)d_out;

    for (int i = 0; i < 3; ++i) {
        const float* xcur = (i == 0) ? x_in : (ws + OFF_X);
        const int mF = 2 * i, mB = 2 * i + 1;
        const int prep_grid = (i == 0) ? 6144 : (i == 1) ? 2304 : 2048;
        prep5_kernel<<<prep_grid, 256, 0, stream>>>(
            xcur, in_w, conv_w, conv_b, xproj_w, dt_w, dt_b, i,
            ws + OFF_XPF, ws + OFF_XPB,
            (unsigned int*)(ws + OFF_XBCF), (unsigned int*)(ws + OFF_XBCB),
            ws + OFF_PKF, ws + OFF_PKB,
            ws + OFF_RESF, ws + OFF_RESB,
            psi_emb, F_w, ws + OFF_WFT, ws + OFF_AEFF, ws + OFF_STT);
        const int scan_grid = (i == 0) ? 1280 : 1024;
        scan8_kernel<<<scan_grid, 256, 0, stream>>>(
            (const unsigned int*)(ws + OFF_XBCF), (const unsigned int*)(ws + OFF_XBCB),
            ws + OFF_PKF, ws + OFF_PKB,
            Alog + mF * 4096, Alog + mB * 4096, ws + OFF_YSF, ws + OFF_YSB,
            psi_emb, psi_s, W_q, W_k, attn_a, ws + OFF_AEFF, ws + OFF_STT);
        const int opfn_grid = (i == 0) ? 768 : (i == 1) ? 512 : 1536;
        opfn4_kernel<<<opfn_grid, 256, 0, stream>>>(
            ws + OFF_YSF, ws + OFF_YSB, ws + OFF_XPF, ws + OFF_XPB,
            ws + OFF_RESF, ws + OFF_RESB,
            Dp, i, xcur, out_w,
            ffn_w1 + i * 4096, ffn_b1 + i * 32, ffn_w2 + i * 4096, ffn_b2 + i * 128,
            ln1_g + i * 128, ln1_b + i * 128, ln2_g + i * 128, ln2_b + i * 128,
            ws + OFF_X,
            ws + OFF_AEFF, ws + OFF_STT,
            ws + OFF_WFT, hmix, (unsigned int*)(ws + OFF_VB));
    }
    // head (post-layer)
    head_ctr_kernel<<<512, 256, 0, stream>>>(
        ws + OFF_X, (const unsigned int*)(ws + OFF_VB), ws + OFF_PART);
    head_red_kernel<<<1024, 128, 0, stream>>>(ws + OFF_PART, ws + OFF_RED1);
    head_out_kernel<<<32, 128, 0, stream>>>(
        ws + OFF_RED1, psi_emb, f_b, hmix, head_w, head_b, outp);
}

// Round 18
// 448.728 us; speedup vs baseline: 1.0673x; 1.0673x over previous
//
#include <hip/hip_runtime.h>
#include <hip/hip_bf16.h>

// MAMBA_BayesMAGAC: B=32, L=512, D=128, E=64, HS=64, DTR=4, U=32, R=3, K=3, DE=10, NH=4
// Round 18: REVERT to round-16 config (best verified: 448.4us). Round 17's
// halo-recompute in-proj regressed (+30us) and is abandoned.
// head_v4 as tail of opfn3(layer2) writing bf16 V into dead PK slot; 13 dispatches.

#define B_ 32
#define L_ 512
#define D_ 128
#define E_ 64
#define HS_ 64

// ---- workspace offsets (floats) ----
#define OFF_X     0u          // 2,097,152  x [b][l][128]
#define OFF_XZF   2097152u    // 2,097,152  xz fwd [b][l][128]
#define OFF_XZB   4194304u
#define OFF_XPF   6291456u    // 1,048,576  xp [b][l][64]
#define OFF_XPB   7340032u
#define OFF_PKF   8388608u    // 2,097,152  (dl,du) [b][l][64][2]
#define OFF_PKB   10485760u
#define OFF_XBCF  12582912u   // 1,048,576 u32 (ends 13,631,488)
#define OFF_WFT   13631488u   // 1,048,576  Wf [h][k][l][n]  (hole 1)
#define OFF_XBCB  14680064u   // 1,048,576 u32 (ends 15,728,640)
#define OFF_STT   15728640u   // 262,144    S^T [h][k][m][n] (hole 2)
#define OFF_AEFF  15990784u   // 65,536     (ends 16,056,320 < YSF)
#define OFF_YSF   16777216u   // 1,048,576  scan y [b][e][l]
#define OFF_YSB   17825792u   // end 18,874,368 floats = 75.5 MB
// head: VB (bf16 V) over dead PK; PART over dead XBC/WfT/StT; RED1 over dead YSF.
#define OFF_VB    8388608u    // u32 x 4,194,304 (ends 12,582,912)
#define OFF_PART  12582912u   // 4,194,304 (ends 16,777,216)
#define OFF_RED1  16777216u   // 131,072

__device__ __forceinline__ float sigf(float x) { return 1.f / (1.f + __expf(-x)); }
__device__ __forceinline__ unsigned int bf16r(float x) {
    unsigned int u = __float_as_uint(x);
    return (u + 0x7fffu + ((u >> 16) & 1u)) >> 16;   // RNE to bf16, return low 16
}

// ---- head-precompute role bodies (device) ----
__device__ void role_wf(int bx0, int tid, const float* __restrict__ psi,
                        const float* __restrict__ F_w, float* __restrict__ WfT)
{
    const int idx = bx0 * 256 + tid;  // 2^20
    const int n = idx & 127, l = (idx >> 7) & 511, k = (idx >> 16) & 3, h = idx >> 18;
    float acc = 0.f;
#pragma unroll
    for (int d = 0; d < 10; ++d)
        acc = fmaf(psi[n * 10 + d], F_w[((h * 10 + d) * 4 + k) * 512 + l], acc);
    WfT[idx] = acc;
}

__device__ void role_qkaeff(int bx0, int tid, const float* __restrict__ psi,
                            const float* __restrict__ psis, const float* __restrict__ W_q,
                            const float* __restrict__ W_k, const float* __restrict__ attn_a,
                            float* __restrict__ Aeff, float* __restrict__ StT,
                            float* sQ2 /*>=32 fl*/, float* red2 /*>=256 fl*/)
{
    const int half = tid >> 7, mcol = tid & 127;
    const int unit = bx0 * 2 + half;                 // 0..511
    const int h = unit >> 7, n = unit & 127;
    float Kreg[10];
#pragma unroll
    for (int d = 0; d < 10; ++d) Kreg[d] = 0.f;
#pragma unroll
    for (int d0 = 0; d0 < 10; ++d0) {
        const float pv = psi[mcol * 10 + d0];
#pragma unroll
        for (int d = 0; d < 10; ++d) Kreg[d] = fmaf(pv, W_k[(d0 * 4 + h) * 10 + d], Kreg[d]);
    }
    if (mcol < 10) {
        float qd = 0.f;
        for (int d0 = 0; d0 < 10; ++d0)
            qd = fmaf(psi[n * 10 + d0], W_q[(d0 * 4 + h) * 10 + mcol], qd);
        sQ2[half * 16 + mcol] = qd;
    }
    __syncthreads();
    float d2 = 0.f;
#pragma unroll
    for (int d = 0; d < 10; ++d) { const float df = psi[n * 10 + d] - psi[mcol * 10 + d]; d2 = fmaf(df, df, d2); }
    const float gv = __expf(-psis[0] * d2);
    float qv = 0.f;
#pragma unroll
    for (int d = 0; d < 10; ++d) qv = fmaf(sQ2[half * 16 + d], Kreg[d], qv);
    qv *= 0.3162277660168379332f;  // 1/sqrt(10)
    float* rd = red2 + half * 128;
    float r;
    rd[mcol] = gv; __syncthreads();
    for (int s = 64; s >= 1; s >>= 1) { if (mcol < s) rd[mcol] = fmaxf(rd[mcol], rd[mcol + s]); __syncthreads(); }
    r = rd[0]; __syncthreads();
    const float eg = __expf(gv - r);
    rd[mcol] = eg; __syncthreads();
    for (int s = 64; s >= 1; s >>= 1) { if (mcol < s) rd[mcol] += rd[mcol + s]; __syncthreads(); }
    const float gsum = rd[0]; __syncthreads();
    rd[mcol] = qv; __syncthreads();
    for (int s = 64; s >= 1; s >>= 1) { if (mcol < s) rd[mcol] = fmaxf(rd[mcol], rd[mcol + s]); __syncthreads(); }
    r = rd[0]; __syncthreads();
    const float eq = __expf(qv - r);
    rd[mcol] = eq; __syncthreads();
    for (int s = 64; s >= 1; s >>= 1) { if (mcol < s) rd[mcol] += rd[mcol + s]; __syncthreads(); }
    const float qsum = rd[0];
    const float al = sigf(attn_a[0]);
    const float aeff = al * (eg / gsum) + (1.f - al) * (eq / qsum);
    Aeff[h * 16384 + n * 128 + mcol] = aeff;
    StT[((h * 4 + 1) * 128 + mcol) * 128 + n] = aeff;
    StT[((h * 4 + 0) * 128 + mcol) * 128 + n] = (mcol == n) ? 1.f : 0.f;
}

__device__ void role_cheb(int bx0, int tid, const float* __restrict__ Aeff,
                          float* __restrict__ StT, int kk)
{
    const int h = bx0 >> 6;
    const int m0 = ((bx0 & 63) << 1) + (tid >> 7);
    const int n = tid & 127;
    const float* Ar = Aeff + h * 16384 + n * 128;
    const float* Sp = StT + ((h * 4 + kk - 1) * 128 + m0) * 128;
    float acc = 0.f;
#pragma unroll 8
    for (int p = 0; p < 128; ++p) acc = fmaf(Ar[p], Sp[p], acc);
    const float s2 = StT[((h * 4 + kk - 2) * 128 + m0) * 128 + n];
    StT[((h * 4 + kk) * 128 + m0) * 128 + n] = 2.f * acc - s2;
}

// V precompute (bf16 out): bx0 in [0,1024)
__device__ void role_v4(int bx0, int tid, const float* __restrict__ StT,
                        const float* __restrict__ WfT, const float* __restrict__ hmix,
                        unsigned int* __restrict__ Vb)
{
    const float m0 = hmix[0], m1 = hmix[1], m2 = hmix[2], m3 = hmix[3];
    const float mxx = fmaxf(fmaxf(m0, m1), fmaxf(m2, m3));
    const float e0 = __expf(m0 - mxx), e1 = __expf(m1 - mxx), e2 = __expf(m2 - mxx), e3 = __expf(m3 - mxx);
    const float inv = 1.f / (e0 + e1 + e2 + e3);
    const float mixv[4] = {e0 * inv, e1 * inv, e2 * inv, e3 * inv};
    const int lt = bx0 & 63, mm = bx0 >> 6;
    const int n4 = tid & 31, mh = tid >> 5;
    const int m = mm * 8 + mh;
    const int l0 = lt * 8, n0 = n4 * 4;
    float4 sv[16];
#pragma unroll
    for (int h = 0; h < 4; ++h) {
        const float mx = mixv[h];
#pragma unroll
        for (int k = 0; k < 4; ++k) {
            const float4 v = *(const float4*)&StT[(size_t)((h * 4 + k) * 128 + m) * 128 + n0];
            sv[h * 4 + k] = float4{v.x * mx, v.y * mx, v.z * mx, v.w * mx};
        }
    }
#pragma unroll
    for (int j = 0; j < 8; ++j) {
        const int l = l0 + j;
        float4 acc = {0.f, 0.f, 0.f, 0.f};
#pragma unroll
        for (int hk = 0; hk < 16; ++hk) {
            const float4 w = *(const float4*)&WfT[(size_t)(hk * 512 + l) * 128 + n0];
            acc.x = fmaf(sv[hk].x, w.x, acc.x);
            acc.y = fmaf(sv[hk].y, w.y, acc.y);
            acc.z = fmaf(sv[hk].z, w.z, acc.z);
            acc.w = fmaf(sv[hk].w, w.w, acc.w);
        }
        const uint2 p = uint2{(bf16r(acc.y) << 16) | bf16r(acc.x),
                              (bf16r(acc.w) << 16) | bf16r(acc.z)};
        *(uint2*)&Vb[(size_t)(l * 128 + m) * 64 + (n0 >> 1)] = p;
    }
}

// ---------------- in-projection (layer 0 only): xz = x @ in_w, 32 rows/block ----------------
__global__ __launch_bounds__(256) void gemm_in2_kernel(
    const float* __restrict__ X, const float* __restrict__ WF, const float* __restrict__ WB,
    float* __restrict__ xzF, float* __restrict__ xzB)
{
    __shared__ float sxT[128][36];    // transposed x tile, padded
    __shared__ float sw[2][16][128];
    const int tid = threadIdx.x;
    const int r0 = blockIdx.x * 32;
    for (int q = tid; q < 1024; q += 256) {
        const int r = q >> 5, k4 = q & 31;
        const float4 v = *(const float4*)&X[(size_t)(r0 + r) * 128 + k4 * 4];
        sxT[k4 * 4 + 0][r] = v.x; sxT[k4 * 4 + 1][r] = v.y;
        sxT[k4 * 4 + 2][r] = v.z; sxT[k4 * 4 + 3][r] = v.w;
    }
    const int wv = tid >> 6, lane = tid & 63;
    const int d = wv >> 1, ch = wv & 1;
    const int r4 = lane >> 4, c16 = lane & 15;
    float4 acc[8];
#pragma unroll
    for (int j = 0; j < 8; ++j) acc[j] = float4{0.f, 0.f, 0.f, 0.f};
    for (int ko = 0; ko < 128; ko += 16) {
        __syncthreads();
        for (int q = tid; q < 1024; q += 256) {
            const int dd = q >> 9, kk = (q >> 5) & 15, c4 = q & 31;
            *(float4*)&sw[dd][kk][c4 * 4] =
                *(const float4*)&((dd ? WB : WF)[(ko + kk) * 128 + c4 * 4]);
        }
        __syncthreads();
#pragma unroll
        for (int kk = 0; kk < 16; ++kk) {
            const float4 w4 = *(const float4*)&sw[d][kk][ch * 64 + c16 * 4];
            const float4 xa = *(const float4*)&sxT[ko + kk][r4 * 8];
            const float4 xb = *(const float4*)&sxT[ko + kk][r4 * 8 + 4];
            const float xs[8] = {xa.x, xa.y, xa.z, xa.w, xb.x, xb.y, xb.z, xb.w};
#pragma unroll
            for (int j = 0; j < 8; ++j) {
                acc[j].x = fmaf(xs[j], w4.x, acc[j].x);
                acc[j].y = fmaf(xs[j], w4.y, acc[j].y);
                acc[j].z = fmaf(xs[j], w4.z, acc[j].z);
                acc[j].w = fmaf(xs[j], w4.w, acc[j].w);
            }
        }
    }
    float* xz = d ? xzB : xzF;
#pragma unroll
    for (int j = 0; j < 8; ++j) {
        *(float4*)&xz[(r0 + r4 * 8 + j) * 128 + ch * 64 + c16 * 4] = acc[j];
    }
}

// ------------- conv + silu + xproj + delta + (tail: wf / cheb3). block 256 -------------
__global__ __launch_bounds__(256) void prep4_kernel(
    const float* __restrict__ xzF_, const float* __restrict__ xzB_,
    const float* __restrict__ conv_w, const float* __restrict__ conv_b,
    const float* __restrict__ xproj_w, const float* __restrict__ dt_w,
    const float* __restrict__ dt_b, int layer,
    float* __restrict__ xpF_, float* __restrict__ xpB_,
    unsigned int* __restrict__ xbcF_, unsigned int* __restrict__ xbcB_,
    float* __restrict__ pkF_, float* __restrict__ pkB_,
    const float* __restrict__ psi, const float* __restrict__ F_w, float* __restrict__ WfT,
    const float* __restrict__ Aeff, float* __restrict__ StT)
{
    __shared__ float sW[8448];
    __shared__ float sxp4[4][64][4];   // [wv][k][it]
    __shared__ float sdl4[4][4][4];    // [wv][it][r]
    const int tid = threadIdx.x, wv = tid >> 6, lane = tid & 63;
    if (blockIdx.x >= 2048) {
        const int bx0 = blockIdx.x - 2048;
        if (layer == 0) role_wf(bx0, tid, psi, F_w, WfT);
        else            role_cheb(bx0, tid, Aeff, StT, 3);
        return;
    }
    const int dir = (int)(blockIdx.x >= 1024);        // block-uniform
    const int r0 = (blockIdx.x & 1023) * 16;          // 16 rows, same b
    const int b = r0 >> 9;
    const int m = layer * 2 + dir;
    const float* Wg = xproj_w + m * 8448;
    for (int q = tid; q < 2112; q += 256) ((float4*)sW)[q] = ((const float4*)Wg)[q];
    const float* xz = dir ? xzB_ : xzF_;
    float* xp  = dir ? xpB_  : xpF_;
    unsigned int* xbc = dir ? xbcB_ : xbcF_;
    float* pkx = dir ? pkB_  : pkF_;
    const float* cw = conv_w + m * 192 + lane * 3;
    const float cw0 = cw[0], cw1 = cw[1], cw2 = cw[2];
    const float cb  = conv_b[m * 64 + lane];
    const float dtb = dt_b[m * 64 + lane];
    const float* dwp = dt_w + m * 256;
    const float dw0 = dwp[lane], dw1 = dwp[64 + lane], dw2 = dwp[128 + lane], dw3 = dwp[192 + lane];
    // conv + silu for the wave's 4 rows
    float uu[4];
#pragma unroll
    for (int it = 0; it < 4; ++it) {
        const int row = r0 + wv * 4 + it;
        const int l = row & 511;
        const int l1 = dir ? l + 1 : l - 1;
        const int l2 = dir ? l + 2 : l - 2;
        float acc = cb;
        const float x0 = xz[(size_t)row * 128 + lane];
        const float x1 = (l1 >= 0 && l1 < 512) ? xz[(size_t)(b * 512 + l1) * 128 + lane] : 0.f;
        const float x2 = (l2 >= 0 && l2 < 512) ? xz[(size_t)(b * 512 + l2) * 128 + lane] : 0.f;
        acc += cw0 * x2 + cw1 * x1 + cw2 * x0;
        const float u = acc * sigf(acc);   // silu
        xp[row * 64 + lane] = u;
        uu[it] = u;
    }
    *(float4*)&sxp4[wv][lane][0] = float4{uu[0], uu[1], uu[2], uu[3]};
    __syncthreads();   // sW ready
    const int jdt = lane & 3;
    float aB[4] = {0.f, 0.f, 0.f, 0.f};
    float aC[4] = {0.f, 0.f, 0.f, 0.f};
    float adt[4] = {0.f, 0.f, 0.f, 0.f};
#pragma unroll 4
    for (int k = 0; k < 64; ++k) {
        const float wB = sW[k * 132 + 4 + lane];
        const float wC = sW[k * 132 + 68 + lane];
        const float wd = sW[k * 132 + jdt];
        const float4 xv = *(const float4*)&sxp4[wv][k][0];
        aB[0] = fmaf(xv.x, wB, aB[0]); aC[0] = fmaf(xv.x, wC, aC[0]); adt[0] = fmaf(xv.x, wd, adt[0]);
        aB[1] = fmaf(xv.y, wB, aB[1]); aC[1] = fmaf(xv.y, wC, aC[1]); adt[1] = fmaf(xv.y, wd, adt[1]);
        aB[2] = fmaf(xv.z, wB, aB[2]); aC[2] = fmaf(xv.z, wC, aC[2]); adt[2] = fmaf(xv.z, wd, adt[2]);
        aB[3] = fmaf(xv.w, wB, aB[3]); aC[3] = fmaf(xv.w, wC, aC[3]); adt[3] = fmaf(xv.w, wd, adt[3]);
    }
#pragma unroll
    for (int it = 0; it < 4; ++it) {
        const int row = r0 + wv * 4 + it;
        xbc[row * 64 + lane] = (bf16r(aC[it]) << 16) | bf16r(aB[it]);
        if (lane < 4) sdl4[wv][it][lane] = adt[it];
    }
#pragma unroll
    for (int it = 0; it < 4; ++it) {
        const int row = r0 + wv * 4 + it;
        float dpre = fmaf(sdl4[wv][it][0], dw0, dtb);
        dpre = fmaf(sdl4[wv][it][1], dw1, dpre);
        dpre = fmaf(sdl4[wv][it][2], dw2, dpre);
        dpre = fmaf(sdl4[wv][it][3], dw3, dpre);
        const float dlt = (dpre > 20.f) ? dpre : log1pf(__expf(dpre));
        ((float2*)pkx)[row * 64 + lane] = float2{dlt, dlt * uu[it]};
    }
}

// ------------- selective scan v8 + (tail: qkaeff). grid 1024(+256), block 256 -------------
__global__ __launch_bounds__(256, 4) void scan8_kernel(
    const unsigned int* __restrict__ xbcF, const unsigned int* __restrict__ xbcB,
    const float* __restrict__ pkF, const float* __restrict__ pkB,
    const float* __restrict__ AlogF, const float* __restrict__ AlogB,
    float* __restrict__ ysF, float* __restrict__ ysB,
    const float* __restrict__ psi, const float* __restrict__ psis,
    const float* __restrict__ W_q, const float* __restrict__ W_k,
    const float* __restrict__ attn_a, float* __restrict__ Aeff, float* __restrict__ StT)
{
    __shared__ unsigned int sbc[2][1024]; // 8 KB
    __shared__ float spk[2][4][16][2];    // 1 KB
    __shared__ float ytile[4][16][68];    // 17.4 KB
    const int tid = threadIdx.x, wv = tid >> 6, lane = tid & 63;
    const int bx = blockIdx.x;
    if (bx >= 1024) {
        role_qkaeff(bx - 1024, tid, psi, psis, W_q, W_k, attn_a, Aeff, StT,
                    (float*)&sbc[1][0], (float*)&sbc[0][0]);
        return;
    }
    const int db = bx & 63;               // (dir,b) in low bits -> same XCD for all e-quads
    const int dir = db >> 5;
    const int b   = db & 31;
    const int e0  = (bx >> 6) * 4;
    const int e   = e0 + wv;
    const unsigned int* xbc = dir ? xbcB : xbcF;
    const float* pk  = dir ? pkB  : pkF;
    const float* Aw  = dir ? AlogB : AlogF;
    float* ys = dir ? ysB : ysF;
    const float a2 = -__expf(Aw[e * 64 + lane]) * 1.4426950408889634f;  // prescaled log2e
    float s = 0.f;
    float* yrow = ys + (size_t)(b * 64 + e) * 512;

    const int psl = tid & 15, pw_ = tid >> 4;

#define STG_LOAD(RS)                                                              \
    {                                                                             \
        nb = *(const uint4*)(xbc + (size_t)(RS) * 64 + tid * 4);                  \
        if (tid < 64)                                                             \
            npp = *(const float2*)(pk + (size_t)((RS) + psl) * 128 + (e0 + pw_) * 2); \
    }
#define STG_WRITE(BUF)                                                            \
    {                                                                             \
        *(uint4*)(&sbc[BUF][tid * 4]) = nb;                                       \
        if (tid < 64) *(float2*)(&spk[BUF][pw_][psl][0]) = npp;                   \
    }

#define SCAN16(REV)                                                               \
    {                                                                             \
        const unsigned int* bc = &sbc[cur][0];                                    \
        const float* pq = &spk[cur][wv][0][0];                                    \
        _Pragma("unroll")                                                         \
        for (int j = 0; j < 8; ++j) {                                             \
            const int pj = (REV) ? 7 - j : j;                                     \
            const float4 pk4 = *(const float4*)(pq + pj * 4);                     \
            const int sA = (REV) ? 15 - 2 * j : 2 * j;                            \
            const int sB = (REV) ? 14 - 2 * j : 2 * j + 1;                        \
            const float dlA = (REV) ? pk4.z : pk4.x;                              \
            const float duA = (REV) ? pk4.w : pk4.y;                              \
            const float dlB = (REV) ? pk4.x : pk4.z;                              \
            const float duB = (REV) ? pk4.y : pk4.w;                              \
            const unsigned int bA = bc[sA * 64 + lane];                           \
            const float BnA = __uint_as_float(bA << 16);                          \
            const float CnA = __uint_as_float(bA & 0xffff0000u);                  \
            s = fmaf(__builtin_amdgcn_exp2f(dlA * a2), s, duA * BnA);             \
            ytile[wv][sA][lane] = s * CnA;                                        \
            const unsigned int bB = bc[sB * 64 + lane];                           \
            const float BnB = __uint_as_float(bB << 16);                          \
            const float CnB = __uint_as_float(bB & 0xffff0000u);                  \
            s = fmaf(__builtin_amdgcn_exp2f(dlB * a2), s, duB * BnB);             \
            ytile[wv][sB][lane] = s * CnB;                                        \
        }                                                                         \
    }

    // prologue: stage tile 0
    {
        uint4 nb; float2 npp;
        const int rs0 = b * 512 + (dir ? 496 : 0);
        STG_LOAD(rs0);
        STG_WRITE(0);
    }
    __syncthreads();

    int cur = 0;
    const int rr = lane & 15, sg = lane >> 4;
    for (int t = 0; t < 32; ++t) {
        uint4 nb; float2 npp;
        const bool more = (t + 1) < 32;
        if (more) {
            const int rs = b * 512 + (dir ? (496 - (t + 1) * 16) : ((t + 1) * 16));
            STG_LOAD(rs);
        }
        if (dir == 0) { SCAN16(0) } else { SCAN16(1) }
        {
            const float* yt = &ytile[wv][rr][sg * 16];
            const float4 A0 = *(const float4*)yt;
            const float4 A1 = *(const float4*)(yt + 4);
            const float4 A2 = *(const float4*)(yt + 8);
            const float4 A3 = *(const float4*)(yt + 12);
            float p = ((A0.x + A0.y) + (A0.z + A0.w)) + ((A1.x + A1.y) + (A1.z + A1.w))
                    + ((A2.x + A2.y) + (A2.z + A2.w)) + ((A3.x + A3.y) + (A3.z + A3.w));
            p += __shfl_xor(p, 16);
            p += __shfl_xor(p, 32);
            if (lane < 16) {
                // slot rr: dir=0 -> l = t*16+rr ; dir=1 -> l = 496 + rr - t*16
                const int lg = dir ? (496 + rr - t * 16) : (t * 16 + rr);
                yrow[lg] = p;
            }
        }
        if (more) STG_WRITE(cur ^ 1);
        __syncthreads();
        cur ^= 1;
    }
#undef STG_LOAD
#undef STG_WRITE
#undef SCAN16
}

// ------------- opfn3 + (tail: layer0 -> cheb2, layer2 -> v4). block 256 -----
__global__ __launch_bounds__(256, 4) void opfn3_kernel(
    const float* __restrict__ ysF, const float* __restrict__ ysB,
    const float* __restrict__ xpF, const float* __restrict__ xpB,
    const float* __restrict__ xzF, const float* __restrict__ xzB,
    const float* __restrict__ Dp, int layer,
    const float* __restrict__ Xc, const float* __restrict__ out_w,
    const float* __restrict__ W1, const float* __restrict__ b1,
    const float* __restrict__ W2, const float* __restrict__ b2,
    const float* __restrict__ g1, const float* __restrict__ bb1,
    const float* __restrict__ g2, const float* __restrict__ bb2,
    float* __restrict__ xout,
    const float* __restrict__ WFn, const float* __restrict__ WBn,
    float* __restrict__ xzFo, float* __restrict__ xzBo,
    const float* __restrict__ Aeff, float* __restrict__ StT,
    const float* __restrict__ WfT, const float* __restrict__ hmix,
    unsigned int* __restrict__ Vb)
{
    __shared__ float smem[9216];
    float* syy = smem;            // [32][128]: sy (gated), then y3, then sxr (time-shared)
    float* sw  = smem + 4096;     // [32][128] weight chunk / W1 / W2
    float* sh  = smem + 8192;     // [32][32]
    const int tid = threadIdx.x;
    if (blockIdx.x >= 512) {
        const int bx0 = blockIdx.x - 512;
        if (layer == 0) role_cheb(bx0, tid, Aeff, StT, 2);
        else            role_v4(bx0, tid, StT, WfT, hmix, Vb);   // layer 2 only
        return;
    }
    const int r0 = blockIdx.x * 32;
    const int b = r0 >> 9, l0 = r0 & 511;
    const int wv = tid >> 6, lane = tid & 63;
    const float* WFp = out_w + (layer * 2) * 8192;
    const float* WBp = out_w + (layer * 2 + 1) * 8192;

    // phase 0: gated transpose: sy[r][d*64+e] = (ys + xp*D) * sigmoid(res)
    for (int q = tid; q < 1024; q += 256) {
        const int d = q >> 9, ee = (q >> 3) & 63, rq = q & 7;
        const float* ysp = d ? ysB : ysF;
        const float4 v = *(const float4*)&ysp[(size_t)(b * 64 + ee) * 512 + l0 + rq * 4];
        const float dv = Dp[(layer * 2 + d) * 64 + ee];
        const float* xpp = d ? xpB : xpF;
        const float* xzp = d ? xzB : xzF;
        const float vv[4] = {v.x, v.y, v.z, v.w};
#pragma unroll
        for (int j = 0; j < 4; ++j) {
            const int r = rq * 4 + j;
            const int row = r0 + r;
            const float u   = xpp[(size_t)row * 64 + ee];
            const float res = xzp[(size_t)row * 128 + 64 + ee];
            syy[r * 128 + d * 64 + ee] = (vv[j] + u * dv) * sigf(res);
        }
    }
    __syncthreads();

    // phase 2: out-proj GEMM (4 chunks of 32 k-rows) + residual + LN1 -> y3 (in syy)
    float acc[8][2];
#pragma unroll
    for (int r = 0; r < 8; ++r) { acc[r][0] = 0.f; acc[r][1] = 0.f; }
#define OPSTEP8(COMP, J)                                                          \
        {                                                                         \
            const float w0 = sw[(kk + (J)) * 128 + lane];                         \
            const float w1 = sw[(kk + (J)) * 128 + lane + 64];                    \
            acc[0][0] = fmaf(y40.COMP, w0, acc[0][0]); acc[0][1] = fmaf(y40.COMP, w1, acc[0][1]); \
            acc[1][0] = fmaf(y41.COMP, w0, acc[1][0]); acc[1][1] = fmaf(y41.COMP, w1, acc[1][1]); \
            acc[2][0] = fmaf(y42.COMP, w0, acc[2][0]); acc[2][1] = fmaf(y42.COMP, w1, acc[2][1]); \
            acc[3][0] = fmaf(y43.COMP, w0, acc[3][0]); acc[3][1] = fmaf(y43.COMP, w1, acc[3][1]); \
            acc[4][0] = fmaf(y44.COMP, w0, acc[4][0]); acc[4][1] = fmaf(y44.COMP, w1, acc[4][1]); \
            acc[5][0] = fmaf(y45.COMP, w0, acc[5][0]); acc[5][1] = fmaf(y45.COMP, w1, acc[5][1]); \
            acc[6][0] = fmaf(y46.COMP, w0, acc[6][0]); acc[6][1] = fmaf(y46.COMP, w1, acc[6][1]); \
            acc[7][0] = fmaf(y47.COMP, w0, acc[7][0]); acc[7][1] = fmaf(y47.COMP, w1, acc[7][1]); \
        }
#define GEMM_CHUNK8(SRC, KO)                                                      \
    _Pragma("unroll")                                                             \
    for (int kk = 0; kk < 32; kk += 4) {                                          \
        const float4 y40 = *(const float4*)&(SRC)[(wv * 8 + 0) * 128 + (KO) + kk];\
        const float4 y41 = *(const float4*)&(SRC)[(wv * 8 + 1) * 128 + (KO) + kk];\
        const float4 y42 = *(const float4*)&(SRC)[(wv * 8 + 2) * 128 + (KO) + kk];\
        const float4 y43 = *(const float4*)&(SRC)[(wv * 8 + 3) * 128 + (KO) + kk];\
        const float4 y44 = *(const float4*)&(SRC)[(wv * 8 + 4) * 128 + (KO) + kk];\
        const float4 y45 = *(const float4*)&(SRC)[(wv * 8 + 5) * 128 + (KO) + kk];\
        const float4 y46 = *(const float4*)&(SRC)[(wv * 8 + 6) * 128 + (KO) + kk];\
        const float4 y47 = *(const float4*)&(SRC)[(wv * 8 + 7) * 128 + (KO) + kk];\
        OPSTEP8(x, 0) OPSTEP8(y, 1) OPSTEP8(z, 2) OPSTEP8(w, 3)                  \
    }
    for (int koi = 0; koi < 4; ++koi) {
        if (koi) __syncthreads();        // readers of sw done
        for (int q = tid; q < 1024; q += 256) {
            const int kk = q >> 5, c4 = q & 31;
            const int kg = koi * 32 + kk;
            *(float4*)&sw[kk * 128 + c4 * 4] = (kg < 64)
                ? *(const float4*)&WFp[kg * 128 + c4 * 4]
                : *(const float4*)&WBp[(kg - 64) * 128 + c4 * 4];
        }
        __syncthreads();
        GEMM_CHUNK8(syy, koi * 32);
    }
    __syncthreads();       // all sy + sw reads done
    // stage W1 (sw free) + LN1 -> y3 (syy free)
    for (int q = tid; q < 1024; q += 256) ((float4*)sw)[q] = ((const float4*)W1)[q];
#pragma unroll
    for (int r = 0; r < 8; ++r) {
        const int rl = wv * 8 + r;
        const int row = r0 + rl;
        float v0 = acc[r][0] + Xc[(size_t)row * 128 + lane];
        float v1 = acc[r][1] + Xc[(size_t)row * 128 + lane + 64];
        float sum = v0 + v1, sq = v0 * v0 + v1 * v1;
#pragma unroll
        for (int o = 32; o >= 1; o >>= 1) { sum += __shfl_xor(sum, o); sq += __shfl_xor(sq, o); }
        const float mean = sum * (1.f / 128.f);
        const float var = sq * (1.f / 128.f) - mean * mean;
        const float rs = rsqrtf(var + 1e-5f);
        syy[rl * 128 + lane]      = (v0 - mean) * rs * g1[lane] + bb1[lane];
        syy[rl * 128 + lane + 64] = (v1 - mean) * rs * g1[lane + 64] + bb1[lane + 64];
    }
    __syncthreads();
    // phase 3: hid = relu(y3 @ W1 + b1) -> sh  (thread: row=tid>>3, 4 u's)
    {
        const int r = tid >> 3, ug = (tid & 7) * 4;
        float h0 = b1[ug], h1 = b1[ug + 1], h2 = b1[ug + 2], h3 = b1[ug + 3];
#pragma unroll 8
        for (int k = 0; k < 128; ++k) {
            const float xv = syy[r * 128 + k];
            h0 = fmaf(xv, sw[k * 32 + ug], h0);
            h1 = fmaf(xv, sw[k * 32 + ug + 1], h1);
            h2 = fmaf(xv, sw[k * 32 + ug + 2], h2);
            h3 = fmaf(xv, sw[k * 32 + ug + 3], h3);
        }
        sh[r * 32 + ug]     = fmaxf(h0, 0.f);
        sh[r * 32 + ug + 1] = fmaxf(h1, 0.f);
        sh[r * 32 + ug + 2] = fmaxf(h2, 0.f);
        sh[r * 32 + ug + 3] = fmaxf(h3, 0.f);
    }
    __syncthreads();
    // stage W2 (sw free after phase 3)
    for (int q = tid; q < 1024; q += 256) ((float4*)sw)[q] = ((const float4*)W2)[q];
    __syncthreads();
    // phase 4: FFN2 + residual(y3) + LN2 -> xout (keep values in regs)
    float xr[8][2];
#pragma unroll
    for (int r = 0; r < 8; ++r) {
        const int rl = wv * 8 + r;
        float a0 = b2[lane], a1 = b2[lane + 64];
#pragma unroll 8
        for (int k = 0; k < 32; ++k) {
            const float hv = sh[rl * 32 + k];
            a0 = fmaf(hv, sw[k * 128 + lane], a0);
            a1 = fmaf(hv, sw[k * 128 + lane + 64], a1);
        }
        const float v0 = a0 + syy[rl * 128 + lane];
        const float v1 = a1 + syy[rl * 128 + lane + 64];
        float sum = v0 + v1, sq = v0 * v0 + v1 * v1;
#pragma unroll
        for (int o = 32; o >= 1; o >>= 1) { sum += __shfl_xor(sum, o); sq += __shfl_xor(sq, o); }
        const float mean = sum * (1.f / 128.f);
        const float var = sq * (1.f / 128.f) - mean * mean;
        const float rs = rsqrtf(var + 1e-5f);
        const int row = r0 + rl;
        const float o0 = (v0 - mean) * rs * g2[lane] + bb2[lane];
        const float o1 = (v1 - mean) * rs * g2[lane + 64] + bb2[lane + 64];
        xout[(size_t)row * 128 + lane]      = o0;
        xout[(size_t)row * 128 + lane + 64] = o1;
        xr[r][0] = o0; xr[r][1] = o1;
    }
    if (WFn == nullptr) return;
    // ---- fused next-layer in-proj: xz_next = xout_tile @ in_w_next ----
    __syncthreads();      // all y3 reads + sw(W2) reads done; syy free -> sxr
    float* sxr = syy;
#pragma unroll
    for (int r = 0; r < 8; ++r) {
        sxr[(wv * 8 + r) * 128 + lane]      = xr[r][0];
        sxr[(wv * 8 + r) * 128 + lane + 64] = xr[r][1];
    }
    for (int c = 0; c < 8; ++c) {
        const int dd = c >> 2, ko = (c & 3) * 32;
        const float* Wn = dd ? WBn : WFn;
        for (int q = tid; q < 1024; q += 256) {
            const int kk = q >> 5, c4 = q & 31;
            *(float4*)&sw[kk * 128 + c4 * 4] = *(const float4*)&Wn[(ko + kk) * 128 + c4 * 4];
        }
        __syncthreads();   // stage visible + (c=0) sxr writes visible
        if ((c & 3) == 0) {
#pragma unroll
            for (int r = 0; r < 8; ++r) { acc[r][0] = 0.f; acc[r][1] = 0.f; }
        }
        GEMM_CHUNK8(sxr, ko);
        if ((c & 3) == 3) {
            float* xzo = dd ? xzBo : xzFo;
#pragma unroll
            for (int r = 0; r < 8; ++r) {
                const int row = r0 + wv * 8 + r;
                xzo[(size_t)row * 128 + lane]      = acc[r][0];
                xzo[(size_t)row * 128 + lane + 64] = acc[r][1];
            }
        }
        __syncthreads();   // sw reads done before next stage
    }
#undef OPSTEP8
#undef GEMM_CHUNK8
}

// ================= head (post-layer) =================
// head_ctr with bf16 V. grid 512 (l), block 256.
__global__ __launch_bounds__(256) void head_ctr_kernel(
    const float* __restrict__ Xf, const unsigned int* __restrict__ Vb,
    float* __restrict__ partial)
{
    __shared__ float sx[32][128];
    const int l = blockIdx.x, tid = threadIdx.x;
    const int n = tid & 127, mh = tid >> 7;
    for (int q = tid; q < 1024; q += 256) {
        const int b = q >> 5, m4 = q & 31;
        *(float4*)&sx[b][m4 * 4] = *(const float4*)&Xf[(size_t)(b * 512 + l) * 128 + m4 * 4];
    }
    __syncthreads();
    float acc[32];
#pragma unroll
    for (int b = 0; b < 32; ++b) acc[b] = 0.f;
    const unsigned int* vp = Vb + (size_t)(l * 128 + mh * 64) * 64 + (n >> 1);
    const bool hi = (n & 1);
    for (int mm = 0; mm < 64; ++mm) {
        const unsigned int u = vp[(size_t)mm * 64];
        const float v = __uint_as_float(hi ? (u & 0xffff0000u) : (u << 16));
        const int m = mh * 64 + mm;
#pragma unroll
        for (int b = 0; b < 32; ++b) acc[b] = fmaf(sx[b][m], v, acc[b]);
    }
#pragma unroll
    for (int b = 0; b < 32; ++b)
        partial[(size_t)((l * 2 + mh) * 32 + b) * 128 + n] = acc[b];
}

__global__ __launch_bounds__(128) void head_red_kernel(
    const float* __restrict__ partial, float* __restrict__ red1)
{
    const int b = blockIdx.x >> 5, cs = blockIdx.x & 31, n = threadIdx.x;
    const float* p = partial + ((size_t)(cs * 32) * 32 + b) * 128 + n;
    float s = 0.f;
#pragma unroll 8
    for (int c = 0; c < 32; ++c) s += p[(size_t)c * 4096];
    red1[(b * 32 + cs) * 128 + n] = s;
}

__global__ __launch_bounds__(128) void head_out_kernel(
    const float* __restrict__ red1, const float* __restrict__ psi,
    const float* __restrict__ f_b, const float* __restrict__ hmix,
    const float* __restrict__ head_w, const float* __restrict__ head_b, float* __restrict__ out)
{
    __shared__ float red[128];
    const int b = blockIdx.x, n = threadIdx.x;
    const float m0 = hmix[0], m1 = hmix[1], m2 = hmix[2], m3 = hmix[3];
    const float mxx = fmaxf(fmaxf(m0, m1), fmaxf(m2, m3));
    const float e0 = __expf(m0 - mxx), e1 = __expf(m1 - mxx), e2 = __expf(m2 - mxx), e3 = __expf(m3 - mxx);
    const float inv = 1.f / (e0 + e1 + e2 + e3);
    const float mixv[4] = {e0 * inv, e1 * inv, e2 * inv, e3 * inv};
    float s = 0.f;
#pragma unroll
    for (int h = 0; h < 4; ++h) {
        float t = 0.f;
#pragma unroll
        for (int d = 0; d < 10; ++d) t = fmaf(psi[n * 10 + d], f_b[h * 10 + d], t);
        s = fmaf(mixv[h], t, s);
    }
#pragma unroll 8
    for (int cs = 0; cs < 32; ++cs) s += red1[(b * 32 + cs) * 128 + n];
    red[n] = s * head_w[n];
    __syncthreads();
    for (int st = 64; st >= 1; st >>= 1) { if (n < st) red[n] += red[n + st]; __syncthreads(); }
    if (n == 0) out[b] = red[0] + head_b[0];
    out[32 + b * 128 + n] = 0.f;   // log_var = zeros
}

extern "C" void kernel_launch(void* const* d_in, const int* in_sizes, int n_in,
                              void* d_out, int out_size, void* d_ws, size_t ws_size,
                              hipStream_t stream) {
    const float* x_in    = (const float*)d_in[0];
    const float* in_w    = (const float*)d_in[1];
    const float* conv_w  = (const float*)d_in[2];
    const float* conv_b  = (const float*)d_in[3];
    const float* xproj_w = (const float*)d_in[4];
    const float* dt_w    = (const float*)d_in[5];
    const float* dt_b    = (const float*)d_in[6];
    const float* Alog    = (const float*)d_in[7];
    const float* Dp      = (const float*)d_in[8];
    const float* out_w   = (const float*)d_in[9];
    const float* ln1_g   = (const float*)d_in[10];
    const float* ln1_b   = (const float*)d_in[11];
    const float* ln2_g   = (const float*)d_in[12];
    const float* ln2_b   = (const float*)d_in[13];
    const float* ffn_w1  = (const float*)d_in[14];
    const float* ffn_b1  = (const float*)d_in[15];
    const float* ffn_w2  = (const float*)d_in[16];
    const float* ffn_b2  = (const float*)d_in[17];
    const float* psi_emb = (const float*)d_in[18];
    const float* psi_s   = (const float*)d_in[19];
    const float* W_q     = (const float*)d_in[20];
    const float* W_k     = (const float*)d_in[21];
    const float* attn_a  = (const float*)d_in[22];
    const float* F_w     = (const float*)d_in[23];
    const float* f_b     = (const float*)d_in[24];
    const float* hmix    = (const float*)d_in[25];
    const float* head_w  = (const float*)d_in[26];
    const float* head_b  = (const float*)d_in[27];
    float* ws = (float*)d_ws;
    float* outp = (float*)d_out;

    gemm_in2_kernel<<<512, 256, 0, stream>>>(
        x_in, in_w, in_w + 16384, ws + OFF_XZF, ws + OFF_XZB);
    for (int i = 0; i < 3; ++i) {
        const float* xcur = (i == 0) ? x_in : (ws + OFF_X);
        const int mF = 2 * i, mB = 2 * i + 1;
        const int prep_grid = (i == 0) ? 6144 : (i == 1) ? 2304 : 2048;
        prep4_kernel<<<prep_grid, 256, 0, stream>>>(
            ws + OFF_XZF, ws + OFF_XZB, conv_w, conv_b, xproj_w, dt_w, dt_b, i,
            ws + OFF_XPF, ws + OFF_XPB,
            (unsigned int*)(ws + OFF_XBCF), (unsigned int*)(ws + OFF_XBCB),
            ws + OFF_PKF, ws + OFF_PKB,
            psi_emb, F_w, ws + OFF_WFT, ws + OFF_AEFF, ws + OFF_STT);
        const int scan_grid = (i == 0) ? 1280 : 1024;
        scan8_kernel<<<scan_grid, 256, 0, stream>>>(
            (const unsigned int*)(ws + OFF_XBCF), (const unsigned int*)(ws + OFF_XBCB),
            ws + OFF_PKF, ws + OFF_PKB,
            Alog + mF * 4096, Alog + mB * 4096, ws + OFF_YSF, ws + OFF_YSB,
            psi_emb, psi_s, W_q, W_k, attn_a, ws + OFF_AEFF, ws + OFF_STT);
        const float* WFn = (i < 2) ? (in_w + (2 * i + 2) * 16384) : nullptr;
        const float* WBn = (i < 2) ? (in_w + (2 * i + 3) * 16384) : nullptr;
        const int opfn_grid = (i == 0) ? 768 : (i == 1) ? 512 : 1536;
        opfn3_kernel<<<opfn_grid, 256, 0, stream>>>(
            ws + OFF_YSF, ws + OFF_YSB, ws + OFF_XPF, ws + OFF_XPB, ws + OFF_XZF, ws + OFF_XZB,
            Dp, i, xcur, out_w,
            ffn_w1 + i * 4096, ffn_b1 + i * 32, ffn_w2 + i * 4096, ffn_b2 + i * 128,
            ln1_g + i * 128, ln1_b + i * 128, ln2_g + i * 128, ln2_b + i * 128,
            ws + OFF_X, WFn, WBn, ws + OFF_XZF, ws + OFF_XZB,
            ws + OFF_AEFF, ws + OFF_STT,
            ws + OFF_WFT, hmix, (unsigned int*)(ws + OFF_VB));
    }
    // head (post-layer)
    head_ctr_kernel<<<512, 256, 0, stream>>>(
        ws + OFF_X, (const unsigned int*)(ws + OFF_VB), ws + OFF_PART);
    head_red_kernel<<<1024, 128, 0, stream>>>(ws + OFF_PART, ws + OFF_RED1);
    head_out_kernel<<<32, 128, 0, stream>>>(
        ws + OFF_RED1, psi_emb, f_b, hmix, head_w, head_b, outp);
}

// Round 19
// 443.666 us; speedup vs baseline: 1.0795x; 1.0114x over previous
//
#include <hip/hip_runtime.h>
#include <hip/hip_bf16.h>

// MAMBA_BayesMAGAC: B=32, L=512, D=128, E=64, HS=64, DTR=4, U=32, R=3, K=3, DE=10, NH=4
// Round 19: opfn3 phase-count halved via 8192-float sw (64-row chunks; out-proj 2 chunks,
// in-proj 4 chunks, W1+W2 co-staged once). LDS 36->52KB. Everything else = round 18.

#define B_ 32
#define L_ 512
#define D_ 128
#define E_ 64
#define HS_ 64

// ---- workspace offsets (floats) ----
#define OFF_X     0u          // 2,097,152  x [b][l][128]
#define OFF_XZF   2097152u    // 2,097,152  xz fwd [b][l][128]
#define OFF_XZB   4194304u
#define OFF_XPF   6291456u    // 1,048,576  xp [b][l][64]
#define OFF_XPB   7340032u
#define OFF_PKF   8388608u    // 2,097,152  (dl,du) [b][l][64][2]
#define OFF_PKB   10485760u
#define OFF_XBCF  12582912u   // 1,048,576 u32 (ends 13,631,488)
#define OFF_WFT   13631488u   // 1,048,576  Wf [h][k][l][n]  (hole 1)
#define OFF_XBCB  14680064u   // 1,048,576 u32 (ends 15,728,640)
#define OFF_STT   15728640u   // 262,144    S^T [h][k][m][n] (hole 2)
#define OFF_AEFF  15990784u   // 65,536     (ends 16,056,320 < YSF)
#define OFF_YSF   16777216u   // 1,048,576  scan y [b][e][l]
#define OFF_YSB   17825792u   // end 18,874,368 floats = 75.5 MB
// head: VB (bf16 V) over dead PK; PART over dead XBC/WfT/StT; RED1 over dead YSF.
#define OFF_VB    8388608u    // u32 x 4,194,304 (ends 12,582,912)
#define OFF_PART  12582912u   // 4,194,304 (ends 16,777,216)
#define OFF_RED1  16777216u   // 131,072

__device__ __forceinline__ float sigf(float x) { return 1.f / (1.f + __expf(-x)); }
__device__ __forceinline__ unsigned int bf16r(float x) {
    unsigned int u = __float_as_uint(x);
    return (u + 0x7fffu + ((u >> 16) & 1u)) >> 16;   // RNE to bf16, return low 16
}

// ---- head-precompute role bodies (device) ----
__device__ void role_wf(int bx0, int tid, const float* __restrict__ psi,
                        const float* __restrict__ F_w, float* __restrict__ WfT)
{
    const int idx = bx0 * 256 + tid;  // 2^20
    const int n = idx & 127, l = (idx >> 7) & 511, k = (idx >> 16) & 3, h = idx >> 18;
    float acc = 0.f;
#pragma unroll
    for (int d = 0; d < 10; ++d)
        acc = fmaf(psi[n * 10 + d], F_w[((h * 10 + d) * 4 + k) * 512 + l], acc);
    WfT[idx] = acc;
}

__device__ void role_qkaeff(int bx0, int tid, const float* __restrict__ psi,
                            const float* __restrict__ psis, const float* __restrict__ W_q,
                            const float* __restrict__ W_k, const float* __restrict__ attn_a,
                            float* __restrict__ Aeff, float* __restrict__ StT,
                            float* sQ2 /*>=32 fl*/, float* red2 /*>=256 fl*/)
{
    const int half = tid >> 7, mcol = tid & 127;
    const int unit = bx0 * 2 + half;                 // 0..511
    const int h = unit >> 7, n = unit & 127;
    float Kreg[10];
#pragma unroll
    for (int d = 0; d < 10; ++d) Kreg[d] = 0.f;
#pragma unroll
    for (int d0 = 0; d0 < 10; ++d0) {
        const float pv = psi[mcol * 10 + d0];
#pragma unroll
        for (int d = 0; d < 10; ++d) Kreg[d] = fmaf(pv, W_k[(d0 * 4 + h) * 10 + d], Kreg[d]);
    }
    if (mcol < 10) {
        float qd = 0.f;
        for (int d0 = 0; d0 < 10; ++d0)
            qd = fmaf(psi[n * 10 + d0], W_q[(d0 * 4 + h) * 10 + mcol], qd);
        sQ2[half * 16 + mcol] = qd;
    }
    __syncthreads();
    float d2 = 0.f;
#pragma unroll
    for (int d = 0; d < 10; ++d) { const float df = psi[n * 10 + d] - psi[mcol * 10 + d]; d2 = fmaf(df, df, d2); }
    const float gv = __expf(-psis[0] * d2);
    float qv = 0.f;
#pragma unroll
    for (int d = 0; d < 10; ++d) qv = fmaf(sQ2[half * 16 + d], Kreg[d], qv);
    qv *= 0.3162277660168379332f;  // 1/sqrt(10)
    float* rd = red2 + half * 128;
    float r;
    rd[mcol] = gv; __syncthreads();
    for (int s = 64; s >= 1; s >>= 1) { if (mcol < s) rd[mcol] = fmaxf(rd[mcol], rd[mcol + s]); __syncthreads(); }
    r = rd[0]; __syncthreads();
    const float eg = __expf(gv - r);
    rd[mcol] = eg; __syncthreads();
    for (int s = 64; s >= 1; s >>= 1) { if (mcol < s) rd[mcol] += rd[mcol + s]; __syncthreads(); }
    const float gsum = rd[0]; __syncthreads();
    rd[mcol] = qv; __syncthreads();
    for (int s = 64; s >= 1; s >>= 1) { if (mcol < s) rd[mcol] = fmaxf(rd[mcol], rd[mcol + s]); __syncthreads(); }
    r = rd[0]; __syncthreads();
    const float eq = __expf(qv - r);
    rd[mcol] = eq; __syncthreads();
    for (int s = 64; s >= 1; s >>= 1) { if (mcol < s) rd[mcol] += rd[mcol + s]; __syncthreads(); }
    const float qsum = rd[0];
    const float al = sigf(attn_a[0]);
    const float aeff = al * (eg / gsum) + (1.f - al) * (eq / qsum);
    Aeff[h * 16384 + n * 128 + mcol] = aeff;
    StT[((h * 4 + 1) * 128 + mcol) * 128 + n] = aeff;
    StT[((h * 4 + 0) * 128 + mcol) * 128 + n] = (mcol == n) ? 1.f : 0.f;
}

__device__ void role_cheb(int bx0, int tid, const float* __restrict__ Aeff,
                          float* __restrict__ StT, int kk)
{
    const int h = bx0 >> 6;
    const int m0 = ((bx0 & 63) << 1) + (tid >> 7);
    const int n = tid & 127;
    const float* Ar = Aeff + h * 16384 + n * 128;
    const float* Sp = StT + ((h * 4 + kk - 1) * 128 + m0) * 128;
    float acc = 0.f;
#pragma unroll 8
    for (int p = 0; p < 128; ++p) acc = fmaf(Ar[p], Sp[p], acc);
    const float s2 = StT[((h * 4 + kk - 2) * 128 + m0) * 128 + n];
    StT[((h * 4 + kk) * 128 + m0) * 128 + n] = 2.f * acc - s2;
}

// V precompute (bf16 out): bx0 in [0,1024)
__device__ void role_v4(int bx0, int tid, const float* __restrict__ StT,
                        const float* __restrict__ WfT, const float* __restrict__ hmix,
                        unsigned int* __restrict__ Vb)
{
    const float m0 = hmix[0], m1 = hmix[1], m2 = hmix[2], m3 = hmix[3];
    const float mxx = fmaxf(fmaxf(m0, m1), fmaxf(m2, m3));
    const float e0 = __expf(m0 - mxx), e1 = __expf(m1 - mxx), e2 = __expf(m2 - mxx), e3 = __expf(m3 - mxx);
    const float inv = 1.f / (e0 + e1 + e2 + e3);
    const float mixv[4] = {e0 * inv, e1 * inv, e2 * inv, e3 * inv};
    const int lt = bx0 & 63, mm = bx0 >> 6;
    const int n4 = tid & 31, mh = tid >> 5;
    const int m = mm * 8 + mh;
    const int l0 = lt * 8, n0 = n4 * 4;
    float4 sv[16];
#pragma unroll
    for (int h = 0; h < 4; ++h) {
        const float mx = mixv[h];
#pragma unroll
        for (int k = 0; k < 4; ++k) {
            const float4 v = *(const float4*)&StT[(size_t)((h * 4 + k) * 128 + m) * 128 + n0];
            sv[h * 4 + k] = float4{v.x * mx, v.y * mx, v.z * mx, v.w * mx};
        }
    }
#pragma unroll
    for (int j = 0; j < 8; ++j) {
        const int l = l0 + j;
        float4 acc = {0.f, 0.f, 0.f, 0.f};
#pragma unroll
        for (int hk = 0; hk < 16; ++hk) {
            const float4 w = *(const float4*)&WfT[(size_t)(hk * 512 + l) * 128 + n0];
            acc.x = fmaf(sv[hk].x, w.x, acc.x);
            acc.y = fmaf(sv[hk].y, w.y, acc.y);
            acc.z = fmaf(sv[hk].z, w.z, acc.z);
            acc.w = fmaf(sv[hk].w, w.w, acc.w);
        }
        const uint2 p = uint2{(bf16r(acc.y) << 16) | bf16r(acc.x),
                              (bf16r(acc.w) << 16) | bf16r(acc.z)};
        *(uint2*)&Vb[(size_t)(l * 128 + m) * 64 + (n0 >> 1)] = p;
    }
}

// ---------------- in-projection (layer 0 only): xz = x @ in_w, 32 rows/block ----------------
__global__ __launch_bounds__(256) void gemm_in2_kernel(
    const float* __restrict__ X, const float* __restrict__ WF, const float* __restrict__ WB,
    float* __restrict__ xzF, float* __restrict__ xzB)
{
    __shared__ float sxT[128][36];    // transposed x tile, padded
    __shared__ float sw[2][16][128];
    const int tid = threadIdx.x;
    const int r0 = blockIdx.x * 32;
    for (int q = tid; q < 1024; q += 256) {
        const int r = q >> 5, k4 = q & 31;
        const float4 v = *(const float4*)&X[(size_t)(r0 + r) * 128 + k4 * 4];
        sxT[k4 * 4 + 0][r] = v.x; sxT[k4 * 4 + 1][r] = v.y;
        sxT[k4 * 4 + 2][r] = v.z; sxT[k4 * 4 + 3][r] = v.w;
    }
    const int wv = tid >> 6, lane = tid & 63;
    const int d = wv >> 1, ch = wv & 1;
    const int r4 = lane >> 4, c16 = lane & 15;
    float4 acc[8];
#pragma unroll
    for (int j = 0; j < 8; ++j) acc[j] = float4{0.f, 0.f, 0.f, 0.f};
    for (int ko = 0; ko < 128; ko += 16) {
        __syncthreads();
        for (int q = tid; q < 1024; q += 256) {
            const int dd = q >> 9, kk = (q >> 5) & 15, c4 = q & 31;
            *(float4*)&sw[dd][kk][c4 * 4] =
                *(const float4*)&((dd ? WB : WF)[(ko + kk) * 128 + c4 * 4]);
        }
        __syncthreads();
#pragma unroll
        for (int kk = 0; kk < 16; ++kk) {
            const float4 w4 = *(const float4*)&sw[d][kk][ch * 64 + c16 * 4];
            const float4 xa = *(const float4*)&sxT[ko + kk][r4 * 8];
            const float4 xb = *(const float4*)&sxT[ko + kk][r4 * 8 + 4];
            const float xs[8] = {xa.x, xa.y, xa.z, xa.w, xb.x, xb.y, xb.z, xb.w};
#pragma unroll
            for (int j = 0; j < 8; ++j) {
                acc[j].x = fmaf(xs[j], w4.x, acc[j].x);
                acc[j].y = fmaf(xs[j], w4.y, acc[j].y);
                acc[j].z = fmaf(xs[j], w4.z, acc[j].z);
                acc[j].w = fmaf(xs[j], w4.w, acc[j].w);
            }
        }
    }
    float* xz = d ? xzB : xzF;
#pragma unroll
    for (int j = 0; j < 8; ++j) {
        *(float4*)&xz[(r0 + r4 * 8 + j) * 128 + ch * 64 + c16 * 4] = acc[j];
    }
}

// ------------- conv + silu + xproj + delta + (tail: wf / cheb3). block 256 -------------
__global__ __launch_bounds__(256) void prep4_kernel(
    const float* __restrict__ xzF_, const float* __restrict__ xzB_,
    const float* __restrict__ conv_w, const float* __restrict__ conv_b,
    const float* __restrict__ xproj_w, const float* __restrict__ dt_w,
    const float* __restrict__ dt_b, int layer,
    float* __restrict__ xpF_, float* __restrict__ xpB_,
    unsigned int* __restrict__ xbcF_, unsigned int* __restrict__ xbcB_,
    float* __restrict__ pkF_, float* __restrict__ pkB_,
    const float* __restrict__ psi, const float* __restrict__ F_w, float* __restrict__ WfT,
    const float* __restrict__ Aeff, float* __restrict__ StT)
{
    __shared__ float sW[8448];
    __shared__ float sxp4[4][64][4];   // [wv][k][it]
    __shared__ float sdl4[4][4][4];    // [wv][it][r]
    const int tid = threadIdx.x, wv = tid >> 6, lane = tid & 63;
    if (blockIdx.x >= 2048) {
        const int bx0 = blockIdx.x - 2048;
        if (layer == 0) role_wf(bx0, tid, psi, F_w, WfT);
        else            role_cheb(bx0, tid, Aeff, StT, 3);
        return;
    }
    const int dir = (int)(blockIdx.x >= 1024);        // block-uniform
    const int r0 = (blockIdx.x & 1023) * 16;          // 16 rows, same b
    const int b = r0 >> 9;
    const int m = layer * 2 + dir;
    const float* Wg = xproj_w + m * 8448;
    for (int q = tid; q < 2112; q += 256) ((float4*)sW)[q] = ((const float4*)Wg)[q];
    const float* xz = dir ? xzB_ : xzF_;
    float* xp  = dir ? xpB_  : xpF_;
    unsigned int* xbc = dir ? xbcB_ : xbcF_;
    float* pkx = dir ? pkB_  : pkF_;
    const float* cw = conv_w + m * 192 + lane * 3;
    const float cw0 = cw[0], cw1 = cw[1], cw2 = cw[2];
    const float cb  = conv_b[m * 64 + lane];
    const float dtb = dt_b[m * 64 + lane];
    const float* dwp = dt_w + m * 256;
    const float dw0 = dwp[lane], dw1 = dwp[64 + lane], dw2 = dwp[128 + lane], dw3 = dwp[192 + lane];
    // conv + silu for the wave's 4 rows
    float uu[4];
#pragma unroll
    for (int it = 0; it < 4; ++it) {
        const int row = r0 + wv * 4 + it;
        const int l = row & 511;
        const int l1 = dir ? l + 1 : l - 1;
        const int l2 = dir ? l + 2 : l - 2;
        float acc = cb;
        const float x0 = xz[(size_t)row * 128 + lane];
        const float x1 = (l1 >= 0 && l1 < 512) ? xz[(size_t)(b * 512 + l1) * 128 + lane] : 0.f;
        const float x2 = (l2 >= 0 && l2 < 512) ? xz[(size_t)(b * 512 + l2) * 128 + lane] : 0.f;
        acc += cw0 * x2 + cw1 * x1 + cw2 * x0;
        const float u = acc * sigf(acc);   // silu
        xp[row * 64 + lane] = u;
        uu[it] = u;
    }
    *(float4*)&sxp4[wv][lane][0] = float4{uu[0], uu[1], uu[2], uu[3]};
    __syncthreads();   // sW ready
    const int jdt = lane & 3;
    float aB[4] = {0.f, 0.f, 0.f, 0.f};
    float aC[4] = {0.f, 0.f, 0.f, 0.f};
    float adt[4] = {0.f, 0.f, 0.f, 0.f};
#pragma unroll 4
    for (int k = 0; k < 64; ++k) {
        const float wB = sW[k * 132 + 4 + lane];
        const float wC = sW[k * 132 + 68 + lane];
        const float wd = sW[k * 132 + jdt];
        const float4 xv = *(const float4*)&sxp4[wv][k][0];
        aB[0] = fmaf(xv.x, wB, aB[0]); aC[0] = fmaf(xv.x, wC, aC[0]); adt[0] = fmaf(xv.x, wd, adt[0]);
        aB[1] = fmaf(xv.y, wB, aB[1]); aC[1] = fmaf(xv.y, wC, aC[1]); adt[1] = fmaf(xv.y, wd, adt[1]);
        aB[2] = fmaf(xv.z, wB, aB[2]); aC[2] = fmaf(xv.z, wC, aC[2]); adt[2] = fmaf(xv.z, wd, adt[2]);
        aB[3] = fmaf(xv.w, wB, aB[3]); aC[3] = fmaf(xv.w, wC, aC[3]); adt[3] = fmaf(xv.w, wd, adt[3]);
    }
#pragma unroll
    for (int it = 0; it < 4; ++it) {
        const int row = r0 + wv * 4 + it;
        xbc[row * 64 + lane] = (bf16r(aC[it]) << 16) | bf16r(aB[it]);
        if (lane < 4) sdl4[wv][it][lane] = adt[it];
    }
#pragma unroll
    for (int it = 0; it < 4; ++it) {
        const int row = r0 + wv * 4 + it;
        float dpre = fmaf(sdl4[wv][it][0], dw0, dtb);
        dpre = fmaf(sdl4[wv][it][1], dw1, dpre);
        dpre = fmaf(sdl4[wv][it][2], dw2, dpre);
        dpre = fmaf(sdl4[wv][it][3], dw3, dpre);
        const float dlt = (dpre > 20.f) ? dpre : log1pf(__expf(dpre));
        ((float2*)pkx)[row * 64 + lane] = float2{dlt, dlt * uu[it]};
    }
}

// ------------- selective scan v8 + (tail: qkaeff). grid 1024(+256), block 256 -------------
__global__ __launch_bounds__(256, 4) void scan8_kernel(
    const unsigned int* __restrict__ xbcF, const unsigned int* __restrict__ xbcB,
    const float* __restrict__ pkF, const float* __restrict__ pkB,
    const float* __restrict__ AlogF, const float* __restrict__ AlogB,
    float* __restrict__ ysF, float* __restrict__ ysB,
    const float* __restrict__ psi, const float* __restrict__ psis,
    const float* __restrict__ W_q, const float* __restrict__ W_k,
    const float* __restrict__ attn_a, float* __restrict__ Aeff, float* __restrict__ StT)
{
    __shared__ unsigned int sbc[2][1024]; // 8 KB
    __shared__ float spk[2][4][16][2];    // 1 KB
    __shared__ float ytile[4][16][68];    // 17.4 KB
    const int tid = threadIdx.x, wv = tid >> 6, lane = tid & 63;
    const int bx = blockIdx.x;
    if (bx >= 1024) {
        role_qkaeff(bx - 1024, tid, psi, psis, W_q, W_k, attn_a, Aeff, StT,
                    (float*)&sbc[1][0], (float*)&sbc[0][0]);
        return;
    }
    const int db = bx & 63;               // (dir,b) in low bits -> same XCD for all e-quads
    const int dir = db >> 5;
    const int b   = db & 31;
    const int e0  = (bx >> 6) * 4;
    const int e   = e0 + wv;
    const unsigned int* xbc = dir ? xbcB : xbcF;
    const float* pk  = dir ? pkB  : pkF;
    const float* Aw  = dir ? AlogB : AlogF;
    float* ys = dir ? ysB : ysF;
    const float a2 = -__expf(Aw[e * 64 + lane]) * 1.4426950408889634f;  // prescaled log2e
    float s = 0.f;
    float* yrow = ys + (size_t)(b * 64 + e) * 512;

    const int psl = tid & 15, pw_ = tid >> 4;

#define STG_LOAD(RS)                                                              \
    {                                                                             \
        nb = *(const uint4*)(xbc + (size_t)(RS) * 64 + tid * 4);                  \
        if (tid < 64)                                                             \
            npp = *(const float2*)(pk + (size_t)((RS) + psl) * 128 + (e0 + pw_) * 2); \
    }
#define STG_WRITE(BUF)                                                            \
    {                                                                             \
        *(uint4*)(&sbc[BUF][tid * 4]) = nb;                                       \
        if (tid < 64) *(float2*)(&spk[BUF][pw_][psl][0]) = npp;                   \
    }

#define SCAN16(REV)                                                               \
    {                                                                             \
        const unsigned int* bc = &sbc[cur][0];                                    \
        const float* pq = &spk[cur][wv][0][0];                                    \
        _Pragma("unroll")                                                         \
        for (int j = 0; j < 8; ++j) {                                             \
            const int pj = (REV) ? 7 - j : j;                                     \
            const float4 pk4 = *(const float4*)(pq + pj * 4);                     \
            const int sA = (REV) ? 15 - 2 * j : 2 * j;                            \
            const int sB = (REV) ? 14 - 2 * j : 2 * j + 1;                        \
            const float dlA = (REV) ? pk4.z : pk4.x;                              \
            const float duA = (REV) ? pk4.w : pk4.y;                              \
            const float dlB = (REV) ? pk4.x : pk4.z;                              \
            const float duB = (REV) ? pk4.y : pk4.w;                              \
            const unsigned int bA = bc[sA * 64 + lane];                           \
            const float BnA = __uint_as_float(bA << 16);                          \
            const float CnA = __uint_as_float(bA & 0xffff0000u);                  \
            s = fmaf(__builtin_amdgcn_exp2f(dlA * a2), s, duA * BnA);             \
            ytile[wv][sA][lane] = s * CnA;                                        \
            const unsigned int bB = bc[sB * 64 + lane];                           \
            const float BnB = __uint_as_float(bB << 16);                          \
            const float CnB = __uint_as_float(bB & 0xffff0000u);                  \
            s = fmaf(__builtin_amdgcn_exp2f(dlB * a2), s, duB * BnB);             \
            ytile[wv][sB][lane] = s * CnB;                                        \
        }                                                                         \
    }

    // prologue: stage tile 0
    {
        uint4 nb; float2 npp;
        const int rs0 = b * 512 + (dir ? 496 : 0);
        STG_LOAD(rs0);
        STG_WRITE(0);
    }
    __syncthreads();

    int cur = 0;
    const int rr = lane & 15, sg = lane >> 4;
    for (int t = 0; t < 32; ++t) {
        uint4 nb; float2 npp;
        const bool more = (t + 1) < 32;
        if (more) {
            const int rs = b * 512 + (dir ? (496 - (t + 1) * 16) : ((t + 1) * 16));
            STG_LOAD(rs);
        }
        if (dir == 0) { SCAN16(0) } else { SCAN16(1) }
        {
            const float* yt = &ytile[wv][rr][sg * 16];
            const float4 A0 = *(const float4*)yt;
            const float4 A1 = *(const float4*)(yt + 4);
            const float4 A2 = *(const float4*)(yt + 8);
            const float4 A3 = *(const float4*)(yt + 12);
            float p = ((A0.x + A0.y) + (A0.z + A0.w)) + ((A1.x + A1.y) + (A1.z + A1.w))
                    + ((A2.x + A2.y) + (A2.z + A2.w)) + ((A3.x + A3.y) + (A3.z + A3.w));
            p += __shfl_xor(p, 16);
            p += __shfl_xor(p, 32);
            if (lane < 16) {
                // slot rr: dir=0 -> l = t*16+rr ; dir=1 -> l = 496 + rr - t*16
                const int lg = dir ? (496 + rr - t * 16) : (t * 16 + rr);
                yrow[lg] = p;
            }
        }
        if (more) STG_WRITE(cur ^ 1);
        __syncthreads();
        cur ^= 1;
    }
#undef STG_LOAD
#undef STG_WRITE
#undef SCAN16
}

// ------------- opfn5: 64-row chunks (half the phases) + (tail: cheb2 / v4). block 256 -----
__global__ __launch_bounds__(256, 3) void opfn5_kernel(
    const float* __restrict__ ysF, const float* __restrict__ ysB,
    const float* __restrict__ xpF, const float* __restrict__ xpB,
    const float* __restrict__ xzF, const float* __restrict__ xzB,
    const float* __restrict__ Dp, int layer,
    const float* __restrict__ Xc, const float* __restrict__ out_w,
    const float* __restrict__ W1, const float* __restrict__ b1,
    const float* __restrict__ W2, const float* __restrict__ b2,
    const float* __restrict__ g1, const float* __restrict__ bb1,
    const float* __restrict__ g2, const float* __restrict__ bb2,
    float* __restrict__ xout,
    const float* __restrict__ WFn, const float* __restrict__ WBn,
    float* __restrict__ xzFo, float* __restrict__ xzBo,
    const float* __restrict__ Aeff, float* __restrict__ StT,
    const float* __restrict__ WfT, const float* __restrict__ hmix,
    unsigned int* __restrict__ Vb)
{
    __shared__ float smem[13312];
    float* syy = smem;            // [32][128] = 4096: sy (gated), then y3, then sxr
    float* sw  = smem + 4096;     // 8192: 64-row weight chunk / (W1 | W2)
    float* sh  = smem + 12288;    // [32][32] = 1024
    const int tid = threadIdx.x;
    if (blockIdx.x >= 512) {
        const int bx0 = blockIdx.x - 512;
        if (layer == 0) role_cheb(bx0, tid, Aeff, StT, 2);
        else            role_v4(bx0, tid, StT, WfT, hmix, Vb);   // layer 2 only
        return;
    }
    const int r0 = blockIdx.x * 32;
    const int b = r0 >> 9, l0 = r0 & 511;
    const int wv = tid >> 6, lane = tid & 63;
    const float* WFp = out_w + (layer * 2) * 8192;
    const float* WBp = out_w + (layer * 2 + 1) * 8192;

    // phase 0: gated transpose: sy[r][d*64+e] = (ys + xp*D) * sigmoid(res)
    for (int q = tid; q < 1024; q += 256) {
        const int d = q >> 9, ee = (q >> 3) & 63, rq = q & 7;
        const float* ysp = d ? ysB : ysF;
        const float4 v = *(const float4*)&ysp[(size_t)(b * 64 + ee) * 512 + l0 + rq * 4];
        const float dv = Dp[(layer * 2 + d) * 64 + ee];
        const float* xpp = d ? xpB : xpF;
        const float* xzp = d ? xzB : xzF;
        const float vv[4] = {v.x, v.y, v.z, v.w};
#pragma unroll
        for (int j = 0; j < 4; ++j) {
            const int r = rq * 4 + j;
            const int row = r0 + r;
            const float u   = xpp[(size_t)row * 64 + ee];
            const float res = xzp[(size_t)row * 128 + 64 + ee];
            syy[r * 128 + d * 64 + ee] = (vv[j] + u * dv) * sigf(res);
        }
    }
    __syncthreads();

    // phase 2: out-proj GEMM — 2 chunks of 64 k-rows (c=0: WF, c=1: WB)
    float acc[8][2];
#pragma unroll
    for (int r = 0; r < 8; ++r) { acc[r][0] = 0.f; acc[r][1] = 0.f; }
#define OPSTEP8(COMP, J)                                                          \
        {                                                                         \
            const float w0 = sw[(kk + (J)) * 128 + lane];                         \
            const float w1 = sw[(kk + (J)) * 128 + lane + 64];                    \
            acc[0][0] = fmaf(y40.COMP, w0, acc[0][0]); acc[0][1] = fmaf(y40.COMP, w1, acc[0][1]); \
            acc[1][0] = fmaf(y41.COMP, w0, acc[1][0]); acc[1][1] = fmaf(y41.COMP, w1, acc[1][1]); \
            acc[2][0] = fmaf(y42.COMP, w0, acc[2][0]); acc[2][1] = fmaf(y42.COMP, w1, acc[2][1]); \
            acc[3][0] = fmaf(y43.COMP, w0, acc[3][0]); acc[3][1] = fmaf(y43.COMP, w1, acc[3][1]); \
            acc[4][0] = fmaf(y44.COMP, w0, acc[4][0]); acc[4][1] = fmaf(y44.COMP, w1, acc[4][1]); \
            acc[5][0] = fmaf(y45.COMP, w0, acc[5][0]); acc[5][1] = fmaf(y45.COMP, w1, acc[5][1]); \
            acc[6][0] = fmaf(y46.COMP, w0, acc[6][0]); acc[6][1] = fmaf(y46.COMP, w1, acc[6][1]); \
            acc[7][0] = fmaf(y47.COMP, w0, acc[7][0]); acc[7][1] = fmaf(y47.COMP, w1, acc[7][1]); \
        }
// 64-deep chunk: sw holds local k-rows 0..63; src col = KO + kk
#define GEMM_CHUNK64(SRC, KO)                                                     \
    _Pragma("unroll")                                                             \
    for (int kk = 0; kk < 64; kk += 4) {                                          \
        const float4 y40 = *(const float4*)&(SRC)[(wv * 8 + 0) * 128 + (KO) + kk];\
        const float4 y41 = *(const float4*)&(SRC)[(wv * 8 + 1) * 128 + (KO) + kk];\
        const float4 y42 = *(const float4*)&(SRC)[(wv * 8 + 2) * 128 + (KO) + kk];\
        const float4 y43 = *(const float4*)&(SRC)[(wv * 8 + 3) * 128 + (KO) + kk];\
        const float4 y44 = *(const float4*)&(SRC)[(wv * 8 + 4) * 128 + (KO) + kk];\
        const float4 y45 = *(const float4*)&(SRC)[(wv * 8 + 5) * 128 + (KO) + kk];\
        const float4 y46 = *(const float4*)&(SRC)[(wv * 8 + 6) * 128 + (KO) + kk];\
        const float4 y47 = *(const float4*)&(SRC)[(wv * 8 + 7) * 128 + (KO) + kk];\
        OPSTEP8(x, 0) OPSTEP8(y, 1) OPSTEP8(z, 2) OPSTEP8(w, 3)                  \
    }
    for (int c = 0; c < 2; ++c) {
        if (c) __syncthreads();          // readers of sw done
        const float* Wp = c ? WBp : WFp;
        for (int q = tid; q < 2048; q += 256) {
            const int kk = q >> 5, c4 = q & 31;
            *(float4*)&sw[kk * 128 + c4 * 4] = *(const float4*)&Wp[kk * 128 + c4 * 4];
        }
        __syncthreads();
        GEMM_CHUNK64(syy, c * 64);
    }
    __syncthreads();       // all sy + sw reads done
    // stage W1 -> sw[0:4096] AND W2 -> sw[4096:8192] (both fit) + LN1 -> y3
    for (int q = tid; q < 1024; q += 256) ((float4*)sw)[q] = ((const float4*)W1)[q];
    for (int q = tid; q < 1024; q += 256) ((float4*)(sw + 4096))[q] = ((const float4*)W2)[q];
#pragma unroll
    for (int r = 0; r < 8; ++r) {
        const int rl = wv * 8 + r;
        const int row = r0 + rl;
        float v0 = acc[r][0] + Xc[(size_t)row * 128 + lane];
        float v1 = acc[r][1] + Xc[(size_t)row * 128 + lane + 64];
        float sum = v0 + v1, sq = v0 * v0 + v1 * v1;
#pragma unroll
        for (int o = 32; o >= 1; o >>= 1) { sum += __shfl_xor(sum, o); sq += __shfl_xor(sq, o); }
        const float mean = sum * (1.f / 128.f);
        const float var = sq * (1.f / 128.f) - mean * mean;
        const float rs = rsqrtf(var + 1e-5f);
        syy[rl * 128 + lane]      = (v0 - mean) * rs * g1[lane] + bb1[lane];
        syy[rl * 128 + lane + 64] = (v1 - mean) * rs * g1[lane + 64] + bb1[lane + 64];
    }
    __syncthreads();   // W1+W2 staged AND y3 ready
    // phase 3: hid = relu(y3 @ W1 + b1) -> sh  (thread: row=tid>>3, 4 u's)
    {
        const int r = tid >> 3, ug = (tid & 7) * 4;
        float h0 = b1[ug], h1 = b1[ug + 1], h2 = b1[ug + 2], h3 = b1[ug + 3];
#pragma unroll 8
        for (int k = 0; k < 128; ++k) {
            const float xv = syy[r * 128 + k];
            h0 = fmaf(xv, sw[k * 32 + ug], h0);
            h1 = fmaf(xv, sw[k * 32 + ug + 1], h1);
            h2 = fmaf(xv, sw[k * 32 + ug + 2], h2);
            h3 = fmaf(xv, sw[k * 32 + ug + 3], h3);
        }
        sh[r * 32 + ug]     = fmaxf(h0, 0.f);
        sh[r * 32 + ug + 1] = fmaxf(h1, 0.f);
        sh[r * 32 + ug + 2] = fmaxf(h2, 0.f);
        sh[r * 32 + ug + 3] = fmaxf(h3, 0.f);
    }
    __syncthreads();   // sh ready (W2 already resident at sw+4096 — no restage)
    // phase 4: FFN2 + residual(y3) + LN2 -> xout (keep values in regs)
    float xr[8][2];
#pragma unroll
    for (int r = 0; r < 8; ++r) {
        const int rl = wv * 8 + r;
        float a0 = b2[lane], a1 = b2[lane + 64];
#pragma unroll 8
        for (int k = 0; k < 32; ++k) {
            const float hv = sh[rl * 32 + k];
            a0 = fmaf(hv, sw[4096 + k * 128 + lane], a0);
            a1 = fmaf(hv, sw[4096 + k * 128 + lane + 64], a1);
        }
        const float v0 = a0 + syy[rl * 128 + lane];
        const float v1 = a1 + syy[rl * 128 + lane + 64];
        float sum = v0 + v1, sq = v0 * v0 + v1 * v1;
#pragma unroll
        for (int o = 32; o >= 1; o >>= 1) { sum += __shfl_xor(sum, o); sq += __shfl_xor(sq, o); }
        const float mean = sum * (1.f / 128.f);
        const float var = sq * (1.f / 128.f) - mean * mean;
        const float rs = rsqrtf(var + 1e-5f);
        const int row = r0 + rl;
        const float o0 = (v0 - mean) * rs * g2[lane] + bb2[lane];
        const float o1 = (v1 - mean) * rs * g2[lane + 64] + bb2[lane + 64];
        xout[(size_t)row * 128 + lane]      = o0;
        xout[(size_t)row * 128 + lane + 64] = o1;
        xr[r][0] = o0; xr[r][1] = o1;
    }
    if (WFn == nullptr) return;
    // ---- fused next-layer in-proj: 4 chunks of 64 k-rows (2 per dir) ----
    __syncthreads();      // all y3 reads + sw reads done; syy free -> sxr
    float* sxr = syy;
#pragma unroll
    for (int r = 0; r < 8; ++r) {
        sxr[(wv * 8 + r) * 128 + lane]      = xr[r][0];
        sxr[(wv * 8 + r) * 128 + lane + 64] = xr[r][1];
    }
    for (int c = 0; c < 4; ++c) {
        const int dd = c >> 1, half = c & 1;
        const float* Wn = dd ? WBn : WFn;
        for (int q = tid; q < 2048; q += 256) {
            const int kk = q >> 5, c4 = q & 31;
            *(float4*)&sw[kk * 128 + c4 * 4] = *(const float4*)&Wn[(half * 64 + kk) * 128 + c4 * 4];
        }
        __syncthreads();   // stage visible + (c=0) sxr writes visible
        if (half == 0) {
#pragma unroll
            for (int r = 0; r < 8; ++r) { acc[r][0] = 0.f; acc[r][1] = 0.f; }
        }
        GEMM_CHUNK64(sxr, half * 64);
        if (half == 1) {
            float* xzo = dd ? xzBo : xzFo;
#pragma unroll
            for (int r = 0; r < 8; ++r) {
                const int row = r0 + wv * 8 + r;
                xzo[(size_t)row * 128 + lane]      = acc[r][0];
                xzo[(size_t)row * 128 + lane + 64] = acc[r][1];
            }
        }
        __syncthreads();   // sw reads done before next stage
    }
#undef OPSTEP8
#undef GEMM_CHUNK64
}

// ================= head (post-layer) =================
// head_ctr with bf16 V. grid 512 (l), block 256.
__global__ __launch_bounds__(256) void head_ctr_kernel(
    const float* __restrict__ Xf, const unsigned int* __restrict__ Vb,
    float* __restrict__ partial)
{
    __shared__ float sx[32][128];
    const int l = blockIdx.x, tid = threadIdx.x;
    const int n = tid & 127, mh = tid >> 7;
    for (int q = tid; q < 1024; q += 256) {
        const int b = q >> 5, m4 = q & 31;
        *(float4*)&sx[b][m4 * 4] = *(const float4*)&Xf[(size_t)(b * 512 + l) * 128 + m4 * 4];
    }
    __syncthreads();
    float acc[32];
#pragma unroll
    for (int b = 0; b < 32; ++b) acc[b] = 0.f;
    const unsigned int* vp = Vb + (size_t)(l * 128 + mh * 64) * 64 + (n >> 1);
    const bool hi = (n & 1);
    for (int mm = 0; mm < 64; ++mm) {
        const unsigned int u = vp[(size_t)mm * 64];
        const float v = __uint_as_float(hi ? (u & 0xffff0000u) : (u << 16));
        const int m = mh * 64 + mm;
#pragma unroll
        for (int b = 0; b < 32; ++b) acc[b] = fmaf(sx[b][m], v, acc[b]);
    }
#pragma unroll
    for (int b = 0; b < 32; ++b)
        partial[(size_t)((l * 2 + mh) * 32 + b) * 128 + n] = acc[b];
}

__global__ __launch_bounds__(128) void head_red_kernel(
    const float* __restrict__ partial, float* __restrict__ red1)
{
    const int b = blockIdx.x >> 5, cs = blockIdx.x & 31, n = threadIdx.x;
    const float* p = partial + ((size_t)(cs * 32) * 32 + b) * 128 + n;
    float s = 0.f;
#pragma unroll 8
    for (int c = 0; c < 32; ++c) s += p[(size_t)c * 4096];
    red1[(b * 32 + cs) * 128 + n] = s;
}

__global__ __launch_bounds__(128) void head_out_kernel(
    const float* __restrict__ red1, const float* __restrict__ psi,
    const float* __restrict__ f_b, const float* __restrict__ hmix,
    const float* __restrict__ head_w, const float* __restrict__ head_b, float* __restrict__ out)
{
    __shared__ float red[128];
    const int b = blockIdx.x, n = threadIdx.x;
    const float m0 = hmix[0], m1 = hmix[1], m2 = hmix[2], m3 = hmix[3];
    const float mxx = fmaxf(fmaxf(m0, m1), fmaxf(m2, m3));
    const float e0 = __expf(m0 - mxx), e1 = __expf(m1 - mxx), e2 = __expf(m2 - mxx), e3 = __expf(m3 - mxx);
    const float inv = 1.f / (e0 + e1 + e2 + e3);
    const float mixv[4] = {e0 * inv, e1 * inv, e2 * inv, e3 * inv};
    float s = 0.f;
#pragma unroll
    for (int h = 0; h < 4; ++h) {
        float t = 0.f;
#pragma unroll
        for (int d = 0; d < 10; ++d) t = fmaf(psi[n * 10 + d], f_b[h * 10 + d], t);
        s = fmaf(mixv[h], t, s);
    }
#pragma unroll 8
    for (int cs = 0; cs < 32; ++cs) s += red1[(b * 32 + cs) * 128 + n];
    red[n] = s * head_w[n];
    __syncthreads();
    for (int st = 64; st >= 1; st >>= 1) { if (n < st) red[n] += red[n + st]; __syncthreads(); }
    if (n == 0) out[b] = red[0] + head_b[0];
    out[32 + b * 128 + n] = 0.f;   // log_var = zeros
}

extern "C" void kernel_launch(void* const* d_in, const int* in_sizes, int n_in,
                              void* d_out, int out_size, void* d_ws, size_t ws_size,
                              hipStream_t stream) {
    const float* x_in    = (const float*)d_in[0];
    const float* in_w    = (const float*)d_in[1];
    const float* conv_w  = (const float*)d_in[2];
    const float* conv_b  = (const float*)d_in[3];
    const float* xproj_w = (const float*)d_in[4];
    const float* dt_w    = (const float*)d_in[5];
    const float* dt_b    = (const float*)d_in[6];
    const float* Alog    = (const float*)d_in[7];
    const float* Dp      = (const float*)d_in[8];
    const float* out_w   = (const float*)d_in[9];
    const float* ln1_g   = (const float*)d_in[10];
    const float* ln1_b   = (const float*)d_in[11];
    const float* ln2_g   = (const float*)d_in[12];
    const float* ln2_b   = (const float*)d_in[13];
    const float* ffn_w1  = (const float*)d_in[14];
    const float* ffn_b1  = (const float*)d_in[15];
    const float* ffn_w2  = (const float*)d_in[16];
    const float* ffn_b2  = (const float*)d_in[17];
    const float* psi_emb = (const float*)d_in[18];
    const float* psi_s   = (const float*)d_in[19];
    const float* W_q     = (const float*)d_in[20];
    const float* W_k     = (const float*)d_in[21];
    const float* attn_a  = (const float*)d_in[22];
    const float* F_w     = (const float*)d_in[23];
    const float* f_b     = (const float*)d_in[24];
    const float* hmix    = (const float*)d_in[25];
    const float* head_w  = (const float*)d_in[26];
    const float* head_b  = (const float*)d_in[27];
    float* ws = (float*)d_ws;
    float* outp = (float*)d_out;

    gemm_in2_kernel<<<512, 256, 0, stream>>>(
        x_in, in_w, in_w + 16384, ws + OFF_XZF, ws + OFF_XZB);
    for (int i = 0; i < 3; ++i) {
        const float* xcur = (i == 0) ? x_in : (ws + OFF_X);
        const int mF = 2 * i, mB = 2 * i + 1;
        const int prep_grid = (i == 0) ? 6144 : (i == 1) ? 2304 : 2048;
        prep4_kernel<<<prep_grid, 256, 0, stream>>>(
            ws + OFF_XZF, ws + OFF_XZB, conv_w, conv_b, xproj_w, dt_w, dt_b, i,
            ws + OFF_XPF, ws + OFF_XPB,
            (unsigned int*)(ws + OFF_XBCF), (unsigned int*)(ws + OFF_XBCB),
            ws + OFF_PKF, ws + OFF_PKB,
            psi_emb, F_w, ws + OFF_WFT, ws + OFF_AEFF, ws + OFF_STT);
        const int scan_grid = (i == 0) ? 1280 : 1024;
        scan8_kernel<<<scan_grid, 256, 0, stream>>>(
            (const unsigned int*)(ws + OFF_XBCF), (const unsigned int*)(ws + OFF_XBCB),
            ws + OFF_PKF, ws + OFF_PKB,
            Alog + mF * 4096, Alog + mB * 4096, ws + OFF_YSF, ws + OFF_YSB,
            psi_emb, psi_s, W_q, W_k, attn_a, ws + OFF_AEFF, ws + OFF_STT);
        const float* WFn = (i < 2) ? (in_w + (2 * i + 2) * 16384) : nullptr;
        const float* WBn = (i < 2) ? (in_w + (2 * i + 3) * 16384) : nullptr;
        const int opfn_grid = (i == 0) ? 768 : (i == 1) ? 512 : 1536;
        opfn5_kernel<<<opfn_grid, 256, 0, stream>>>(
            ws + OFF_YSF, ws + OFF_YSB, ws + OFF_XPF, ws + OFF_XPB, ws + OFF_XZF, ws + OFF_XZB,
            Dp, i, xcur, out_w,
            ffn_w1 + i * 4096, ffn_b1 + i * 32, ffn_w2 + i * 4096, ffn_b2 + i * 128,
            ln1_g + i * 128, ln1_b + i * 128, ln2_g + i * 128, ln2_b + i * 128,
            ws + OFF_X, WFn, WBn, ws + OFF_XZF, ws + OFF_XZB,
            ws + OFF_AEFF, ws + OFF_STT,
            ws + OFF_WFT, hmix, (unsigned int*)(ws + OFF_VB));
    }
    // head (post-layer)
    head_ctr_kernel<<<512, 256, 0, stream>>>(
        ws + OFF_X, (const unsigned int*)(ws + OFF_VB), ws + OFF_PART);
    head_red_kernel<<<1024, 128, 0, stream>>>(ws + OFF_PART, ws + OFF_RED1);
    head_out_kernel<<<32, 128, 0, stream>>>(
        ws + OFF_RED1, psi_emb, f_b, hmix, head_w, head_b, outp);
}